// Round 1
// baseline (346.336 us; speedup 1.0000x reference)
//
#include <hip/hip_runtime.h>
#include <math.h>

#define N_RAYS 16384
#define S 128          // coarse steps
#define U 128          // upsample steps
#define TT 256         // total samples
#define FEAT 15
#define IMG_DIMS 4
#define BOUNDF 2.0f
#define MIN_NEAR 0.05f

__device__ __forceinline__ float softplus_f(float x) {
    return fmaxf(x, 0.0f) + log1pf(__expf(-fabsf(x)));
}
__device__ __forceinline__ float sigmoid_f(float x) {
    return 1.0f / (1.0f + __expf(-x));
}
__device__ __forceinline__ float clampf(float x, float lo, float hi) {
    return fminf(fmaxf(x, lo), hi);
}

extern "C" __global__ __launch_bounds__(128)
void nerf_render_kernel(const float* __restrict__ rays_o,
                        const float* __restrict__ rays_d,
                        const float* __restrict__ W1, const float* __restrict__ b1,
                        const float* __restrict__ W2, const float* __restrict__ b2,
                        const float* __restrict__ Wc, const float* __restrict__ Wd,
                        const float* __restrict__ bc,
                        float* __restrict__ out) {
    const int ray  = blockIdx.x;
    const int tid  = threadIdx.x;
    const int lane = tid & 63;
    const int wv   = tid >> 6;

    __shared__ float s_z[TT];        // [0..127] coarse z, [128..255] fine z
    __shared__ float s_zs[TT];       // sorted z
    __shared__ float s_sigma[TT];
    __shared__ int   s_src[TT];      // sorted position -> source sample index
    __shared__ float s_cdf[S];       // 127 used
    __shared__ float s_scan[S];
    __shared__ float s_tmp[16];
    __shared__ float s_feat[TT][FEAT];

    // ---- ray setup (uniform per block) ----
    const float ox = rays_o[ray * 3 + 0], oy = rays_o[ray * 3 + 1], oz = rays_o[ray * 3 + 2];
    const float dx = rays_d[ray * 3 + 0], dy = rays_d[ray * 3 + 1], dz = rays_d[ray * 3 + 2];

    auto invd = [](float d) { float dd = (fabsf(d) < 1e-9f) ? 1e-9f : d; return 1.0f / dd; };
    const float ixv = invd(dx), iyv = invd(dy), izv = invd(dz);
    const float t1x = (-BOUNDF - ox) * ixv, t2x = (BOUNDF - ox) * ixv;
    const float t1y = (-BOUNDF - oy) * iyv, t2y = (BOUNDF - oy) * iyv;
    const float t1z = (-BOUNDF - oz) * izv, t2z = (BOUNDF - oz) * izv;
    float nearv = fmaxf(fmaxf(fminf(t1x, t2x), fminf(t1y, t2y)), fminf(t1z, t2z));
    nearv = fmaxf(nearv, MIN_NEAR);
    float farv = fminf(fminf(fmaxf(t1x, t2x), fmaxf(t1y, t2y)), fmaxf(t1z, t2z));
    farv = fmaxf(farv, nearv + 1e-5f);
    const float sample_dist = (farv - nearv) * (1.0f / (float)S);

    // ---- MLP: x -> (sigma, feat[15]); weights are uniform -> scalar loads ----
    auto mlp = [&](float z, float* featout, float& sigma) {
        const float x0 = clampf(ox + dx * z, -BOUNDF, BOUNDF);
        const float x1 = clampf(oy + dy * z, -BOUNDF, BOUNDF);
        const float x2 = clampf(oz + dz * z, -BOUNDF, BOUNDF);
        float acc[16];
#pragma unroll
        for (int c = 0; c < 16; ++c) acc[c] = b2[c];
#pragma unroll
        for (int j = 0; j < 32; ++j) {
            float h = b1[j] + x0 * W1[j] + x1 * W1[32 + j] + x2 * W1[64 + j];
            h = fmaxf(h, 0.0f);
#pragma unroll
            for (int c = 0; c < 16; ++c) acc[c] += h * W2[j * 16 + c];
        }
        sigma = softplus_f(acc[0]);
#pragma unroll
        for (int k = 0; k < FEAT; ++k) featout[k] = acc[k + 1];
    };

    // ---- coarse pass: one sample per thread ----
    const float zc = nearv + (farv - nearv) * ((float)tid * (1.0f / (float)(S - 1)));
    float sigc;
    mlp(zc, &s_feat[tid][0], sigc);
    s_z[tid] = zc;
    s_sigma[tid] = sigc;
    __syncthreads();

    // ---- coarse composite weights (for PDF) ----
    const float delta_c = (tid < S - 1) ? (s_z[tid + 1] - zc) : sample_dist;
    const float alpha_c = 1.0f - __expf(-delta_c * sigc);
    const float v_c = 1.0f - alpha_c + 1e-15f;
    // inclusive multiplicative scan over 128 (wave shfl + cross-wave)
    float inc = v_c;
#pragma unroll
    for (int off = 1; off < 64; off <<= 1) {
        float y = __shfl_up(inc, off, 64);
        if (lane >= off) inc *= y;
    }
    if (lane == 63) s_tmp[wv] = inc;
    __syncthreads();
    if (wv == 1) inc *= s_tmp[0];
    __syncthreads();
    s_scan[tid] = inc;
    __syncthreads();
    const float T_c = (tid == 0) ? 1.0f : s_scan[tid - 1];
    const float w_coarse = alpha_c * T_c;
    __syncthreads();
    s_scan[tid] = w_coarse;
    __syncthreads();
    // pdf over bins j=0..125 uses w[1..126]
    float pw = (tid < 126) ? (s_scan[tid + 1] + 1e-5f) : 0.0f;
    float cs = pw;
#pragma unroll
    for (int off = 1; off < 64; off <<= 1) {
        float y = __shfl_up(cs, off, 64);
        if (lane >= off) cs += y;
    }
    if (lane == 63) s_tmp[wv + 4] = cs;
    __syncthreads();
    if (wv == 1) cs += s_tmp[4];
    __syncthreads();
    if (tid == 125) s_tmp[2] = cs;   // total (unnormalized)
    __syncthreads();
    const float rtot = 1.0f / s_tmp[2];
    if (tid == 0) s_cdf[0] = 0.0f;
    if (tid < 126) s_cdf[tid + 1] = cs * rtot;
    __syncthreads();

    // ---- inverse-CDF fine sampling: one sample per thread ----
    const float u = (1.0f + 2.0f * (float)tid) * (1.0f / 256.0f);
    int lo = 0, hi = 127;
    while (lo < hi) { int m = (lo + hi) >> 1; if (s_cdf[m] <= u) lo = m + 1; else hi = m; }
    const int inds = lo;                       // in [1,127]
    const int below = inds - 1;                // <= 126
    const int above = (inds > 126) ? 126 : inds;
    const float cdf_b = s_cdf[below], cdf_a = s_cdf[above];
    const float bins_b = 0.5f * (s_z[below] + s_z[below + 1]);
    const float bins_a = 0.5f * (s_z[above] + s_z[above + 1]);
    float denom = cdf_a - cdf_b;
    if (denom < 1e-5f) denom = 1.0f;
    const float tfrac = (u - cdf_b) / denom;
    const float zf = bins_b + tfrac * (bins_a - bins_b);

    float sigf;
    mlp(zf, &s_feat[S + tid][0], sigf);
    s_z[S + tid] = zf;
    s_sigma[S + tid] = sigf;
    __syncthreads();

    // ---- stable merge of two sorted lists (== stable argsort of concat) ----
    {   // coarse element tid: dest = tid + #{fine < zc}
        int l2 = 0, h2 = U;
        while (l2 < h2) { int m = (l2 + h2) >> 1; if (s_z[S + m] < zc) l2 = m + 1; else h2 = m; }
        const int dest = tid + l2;
        s_zs[dest] = zc; s_src[dest] = tid;
    }
    {   // fine element tid: dest = tid + #{coarse <= zf}
        int l2 = 0, h2 = S;
        while (l2 < h2) { int m = (l2 + h2) >> 1; if (s_z[m] <= zf) l2 = m + 1; else h2 = m; }
        const int dest = tid + l2;
        s_zs[dest] = zf; s_src[dest] = S + tid;
    }
    __syncthreads();

    // ---- final compositing: 2 sorted samples per thread ----
    const int p0 = 2 * tid, p1 = 2 * tid + 1;
    const float z0 = s_zs[p0], z1 = s_zs[p1];
    const float d0 = z1 - z0;
    const float d1 = (tid == 127) ? sample_dist : (s_zs[p1 + 1] - z1);
    const int src0 = s_src[p0], src1 = s_src[p1];
    const float sg0 = s_sigma[src0], sg1 = s_sigma[src1];
    const float a0 = 1.0f - __expf(-d0 * sg0);
    const float a1 = 1.0f - __expf(-d1 * sg1);
    const float v0 = 1.0f - a0 + 1e-15f;
    const float v1 = 1.0f - a1 + 1e-15f;
    const float pp = v0 * v1;
    float inc2 = pp;
#pragma unroll
    for (int off = 1; off < 64; off <<= 1) {
        float y = __shfl_up(inc2, off, 64);
        if (lane >= off) inc2 *= y;
    }
    if (lane == 63) s_tmp[8 + wv] = inc2;
    __syncthreads();
    if (wv == 1) inc2 *= s_tmp[8];
    __syncthreads();
    s_scan[tid] = inc2;
    __syncthreads();
    const float e = (tid == 0) ? 1.0f : s_scan[tid - 1];
    const float T0 = e, T1 = e * v0;
    const float w0 = a0 * T0, w1 = a1 * T1;

    // rgb = sigmoid(feat @ Wc + d @ Wd + bc)
    float dvec[4];
#pragma unroll
    for (int c = 0; c < 4; ++c)
        dvec[c] = bc[c] + dx * Wd[c] + dy * Wd[4 + c] + dz * Wd[8 + c];
    float acc0[4], acc1[4];
#pragma unroll
    for (int c = 0; c < 4; ++c) { acc0[c] = dvec[c]; acc1[c] = dvec[c]; }
#pragma unroll
    for (int k = 0; k < FEAT; ++k) {
        const float f0 = s_feat[src0][k];
        const float f1 = s_feat[src1][k];
#pragma unroll
        for (int c = 0; c < 4; ++c) {
            acc0[c] += f0 * Wc[k * 4 + c];
            acc1[c] += f1 * Wc[k * 4 + c];
        }
    }

    const float inv_fn = 1.0f / (farv - nearv);
    const float oz0 = clampf((z0 - nearv) * inv_fn, 0.0f, 1.0f);
    const float oz1 = clampf((z1 - nearv) * inv_fn, 0.0f, 1.0f);

    float vals[6];
#pragma unroll
    for (int c = 0; c < 4; ++c)
        vals[c] = w0 * sigmoid_f(acc0[c]) + w1 * sigmoid_f(acc1[c]);
    vals[4] = w0 * oz0 + w1 * oz1;       // depth partial
    vals[5] = w0 + w1;                   // weights_sum partial

    // reduce 6 values over 128 threads
#pragma unroll
    for (int q = 0; q < 6; ++q) {
        float v = vals[q];
#pragma unroll
        for (int off = 32; off; off >>= 1) v += __shfl_down(v, off, 64);
        vals[q] = v;
    }
    if (lane == 0) {
#pragma unroll
        for (int q = 0; q < 6; ++q) s_tmp[wv * 8 + q] = vals[q];
    }
    __syncthreads();
    if (tid == 0) {
        const float wsum = s_tmp[5] + s_tmp[13];
        const float dep  = s_tmp[4] + s_tmp[12];
#pragma unroll
        for (int c = 0; c < 4; ++c)
            out[ray * 4 + c] = (s_tmp[c] + s_tmp[8 + c]) + (1.0f - wsum);
        out[4 * N_RAYS + ray] = dep;
        out[5 * N_RAYS + ray] = wsum;
    }
}

extern "C" void kernel_launch(void* const* d_in, const int* in_sizes, int n_in,
                              void* d_out, int out_size, void* d_ws, size_t ws_size,
                              hipStream_t stream) {
    const float* rays_o = (const float*)d_in[0];
    const float* rays_d = (const float*)d_in[1];
    const float* W1 = (const float*)d_in[2];
    const float* b1 = (const float*)d_in[3];
    const float* W2 = (const float*)d_in[4];
    const float* b2 = (const float*)d_in[5];
    const float* Wc = (const float*)d_in[6];
    const float* Wd = (const float*)d_in[7];
    const float* bc = (const float*)d_in[8];
    float* out = (float*)d_out;

    hipLaunchKernelGGL(nerf_render_kernel, dim3(N_RAYS), dim3(128), 0, stream,
                       rays_o, rays_d, W1, b1, W2, b2, Wc, Wd, bc, out);
}

// Round 2
// 81.891 us; speedup vs baseline: 4.2292x; 4.2292x over previous
//
#include <hip/hip_runtime.h>
#include <math.h>

#define N_RAYS 16384
#define S 128          // coarse steps
#define U 128          // upsample steps
#define TT 256         // total samples
#define FEAT 15
#define BOUNDF 2.0f
#define MIN_NEAR 0.05f

// d_ws float layout: [0..127] Wfused[j*4+c], [128..131] bfused[c],
//                    [132..163] W2col0[j],   [164] b2_0
#define WS_WFUSED 0
#define WS_BFUSED 128
#define WS_W2COL0 132
#define WS_B20    164

__device__ __forceinline__ float softplus_f(float x) {
    return fmaxf(x, 0.0f) + log1pf(__expf(-fabsf(x)));
}
__device__ __forceinline__ float sigmoid_f(float x) {
    return 1.0f / (1.0f + __expf(-x));
}
__device__ __forceinline__ float clampf(float x, float lo, float hi) {
    return fminf(fmaxf(x, lo), hi);
}

extern "C" __global__ __launch_bounds__(128)
void nerf_prep_kernel(const float* __restrict__ W2, const float* __restrict__ b2,
                      const float* __restrict__ Wc, const float* __restrict__ bc,
                      float* __restrict__ ws) {
    const int t = threadIdx.x;          // 128 threads
    const int j = t >> 2, c = t & 3;
    float acc = 0.0f;
#pragma unroll
    for (int k = 0; k < FEAT; ++k) acc += W2[j * 16 + 1 + k] * Wc[k * 4 + c];
    ws[WS_WFUSED + j * 4 + c] = acc;
    if (t < 4) {
        float b = bc[t];
#pragma unroll
        for (int k = 0; k < FEAT; ++k) b += b2[1 + k] * Wc[k * 4 + t];
        ws[WS_BFUSED + t] = b;
    }
    if (t < 32) ws[WS_W2COL0 + t] = W2[t * 16];
    if (t == 0) ws[WS_B20] = b2[0];
}

extern "C" __global__ __launch_bounds__(128)
void nerf_render_kernel(const float* __restrict__ rays_o,
                        const float* __restrict__ rays_d,
                        const float* __restrict__ W1, const float* __restrict__ b1,
                        const float* __restrict__ Wd,
                        const float* __restrict__ wsf,
                        float* __restrict__ out) {
    const int ray  = blockIdx.x;
    const int tid  = threadIdx.x;
    const int lane = tid & 63;
    const int wv   = tid >> 6;

    __shared__ float  s_z[TT];        // [0..127] coarse z, [128..255] fine z
    __shared__ float  s_zs[TT];       // sorted z
    __shared__ float  s_sigma[TT];
    __shared__ int    s_src[TT];      // sorted position -> source sample index
    __shared__ float  s_cdf[S];       // 127 used
    __shared__ float  s_scan[S];
    __shared__ float  s_tmp[16];
    __shared__ float4 s_rgb[TT];      // sigmoided rgb per sample

    // ---- ray setup (uniform per block) ----
    const float ox = rays_o[ray * 3 + 0], oy = rays_o[ray * 3 + 1], oz = rays_o[ray * 3 + 2];
    const float dx = rays_d[ray * 3 + 0], dy = rays_d[ray * 3 + 1], dz = rays_d[ray * 3 + 2];

    auto invd = [](float d) { float dd = (fabsf(d) < 1e-9f) ? 1e-9f : d; return 1.0f / dd; };
    const float ixv = invd(dx), iyv = invd(dy), izv = invd(dz);
    const float t1x = (-BOUNDF - ox) * ixv, t2x = (BOUNDF - ox) * ixv;
    const float t1y = (-BOUNDF - oy) * iyv, t2y = (BOUNDF - oy) * iyv;
    const float t1z = (-BOUNDF - oz) * izv, t2z = (BOUNDF - oz) * izv;
    float nearv = fmaxf(fmaxf(fminf(t1x, t2x), fminf(t1y, t2y)), fminf(t1z, t2z));
    nearv = fmaxf(nearv, MIN_NEAR);
    float farv = fminf(fminf(fmaxf(t1x, t2x), fmaxf(t1y, t2y)), fmaxf(t1z, t2z));
    farv = fmaxf(farv, nearv + 1e-5f);
    const float sample_dist = (farv - nearv) * (1.0f / (float)S);

    // per-ray rgb bias: bfused + d @ Wd
    float rayc[4];
#pragma unroll
    for (int c = 0; c < 4; ++c)
        rayc[c] = wsf[WS_BFUSED + c] + dx * Wd[c] + dy * Wd[4 + c] + dz * Wd[8 + c];
    const float b2_0 = wsf[WS_B20];

    // ---- fused MLP: x -> (sigma, sigmoid(rgb logits)) ----
    auto mlp = [&](float z, float4& rgb, float& sigma) {
        const float x0 = clampf(ox + dx * z, -BOUNDF, BOUNDF);
        const float x1 = clampf(oy + dy * z, -BOUNDF, BOUNDF);
        const float x2 = clampf(oz + dz * z, -BOUNDF, BOUNDF);
        float acc_s = b2_0;
        float a0 = rayc[0], a1 = rayc[1], a2 = rayc[2], a3 = rayc[3];
#pragma unroll
        for (int j = 0; j < 32; ++j) {
            float h = b1[j] + x0 * W1[j] + x1 * W1[32 + j] + x2 * W1[64 + j];
            h = fmaxf(h, 0.0f);
            acc_s += h * wsf[WS_W2COL0 + j];
            a0 += h * wsf[WS_WFUSED + j * 4 + 0];
            a1 += h * wsf[WS_WFUSED + j * 4 + 1];
            a2 += h * wsf[WS_WFUSED + j * 4 + 2];
            a3 += h * wsf[WS_WFUSED + j * 4 + 3];
        }
        sigma = softplus_f(acc_s);
        rgb.x = sigmoid_f(a0); rgb.y = sigmoid_f(a1);
        rgb.z = sigmoid_f(a2); rgb.w = sigmoid_f(a3);
    };

    // ---- coarse pass: one sample per thread ----
    const float zc = nearv + (farv - nearv) * ((float)tid * (1.0f / (float)(S - 1)));
    float sigc; float4 rgbc;
    mlp(zc, rgbc, sigc);
    s_z[tid] = zc;
    s_sigma[tid] = sigc;
    s_rgb[tid] = rgbc;
    __syncthreads();

    // ---- coarse composite weights (for PDF) ----
    const float delta_c = (tid < S - 1) ? (s_z[tid + 1] - zc) : sample_dist;
    const float alpha_c = 1.0f - __expf(-delta_c * sigc);
    const float v_c = 1.0f - alpha_c + 1e-15f;
    float inc = v_c;
#pragma unroll
    for (int off = 1; off < 64; off <<= 1) {
        float y = __shfl_up(inc, off, 64);
        if (lane >= off) inc *= y;
    }
    if (lane == 63) s_tmp[wv] = inc;
    __syncthreads();
    if (wv == 1) inc *= s_tmp[0];
    __syncthreads();
    s_scan[tid] = inc;
    __syncthreads();
    const float T_c = (tid == 0) ? 1.0f : s_scan[tid - 1];
    const float w_coarse = alpha_c * T_c;
    __syncthreads();
    s_scan[tid] = w_coarse;
    __syncthreads();
    // pdf over bins j=0..125 uses w[1..126]
    float pw = (tid < 126) ? (s_scan[tid + 1] + 1e-5f) : 0.0f;
    float cs = pw;
#pragma unroll
    for (int off = 1; off < 64; off <<= 1) {
        float y = __shfl_up(cs, off, 64);
        if (lane >= off) cs += y;
    }
    if (lane == 63) s_tmp[wv + 4] = cs;
    __syncthreads();
    if (wv == 1) cs += s_tmp[4];
    __syncthreads();
    if (tid == 125) s_tmp[2] = cs;   // total (unnormalized)
    __syncthreads();
    const float rtot = 1.0f / s_tmp[2];
    if (tid == 0) s_cdf[0] = 0.0f;
    if (tid < 126) s_cdf[tid + 1] = cs * rtot;
    __syncthreads();

    // ---- inverse-CDF fine sampling: one sample per thread ----
    const float u = (1.0f + 2.0f * (float)tid) * (1.0f / 256.0f);
    int lo = 0, hi = 127;
    while (lo < hi) { int m = (lo + hi) >> 1; if (s_cdf[m] <= u) lo = m + 1; else hi = m; }
    const int inds = lo;                       // in [1,127]
    const int below = inds - 1;                // <= 126
    const int above = (inds > 126) ? 126 : inds;
    const float cdf_b = s_cdf[below], cdf_a = s_cdf[above];
    const float bins_b = 0.5f * (s_z[below] + s_z[below + 1]);
    const float bins_a = 0.5f * (s_z[above] + s_z[above + 1]);
    float denom = cdf_a - cdf_b;
    if (denom < 1e-5f) denom = 1.0f;
    const float tfrac = (u - cdf_b) / denom;
    const float zf = bins_b + tfrac * (bins_a - bins_b);

    float sigf; float4 rgbf;
    mlp(zf, rgbf, sigf);
    s_z[S + tid] = zf;
    s_sigma[S + tid] = sigf;
    s_rgb[S + tid] = rgbf;
    __syncthreads();

    // ---- stable merge of two sorted lists (== stable argsort of concat) ----
    {   // coarse element tid: dest = tid + #{fine < zc}
        int l2 = 0, h2 = U;
        while (l2 < h2) { int m = (l2 + h2) >> 1; if (s_z[S + m] < zc) l2 = m + 1; else h2 = m; }
        const int dest = tid + l2;
        s_zs[dest] = zc; s_src[dest] = tid;
    }
    {   // fine element tid: dest = tid + #{coarse <= zf}
        int l2 = 0, h2 = S;
        while (l2 < h2) { int m = (l2 + h2) >> 1; if (s_z[m] <= zf) l2 = m + 1; else h2 = m; }
        const int dest = tid + l2;
        s_zs[dest] = zf; s_src[dest] = S + tid;
    }
    __syncthreads();

    // ---- final compositing: 2 sorted samples per thread ----
    const int p0 = 2 * tid, p1 = 2 * tid + 1;
    const float z0 = s_zs[p0], z1 = s_zs[p1];
    const float d0 = z1 - z0;
    const float d1 = (tid == 127) ? sample_dist : (s_zs[p1 + 1] - z1);
    const int src0 = s_src[p0], src1 = s_src[p1];
    const float sg0 = s_sigma[src0], sg1 = s_sigma[src1];
    const float a0 = 1.0f - __expf(-d0 * sg0);
    const float a1 = 1.0f - __expf(-d1 * sg1);
    const float v0 = 1.0f - a0 + 1e-15f;
    const float v1 = 1.0f - a1 + 1e-15f;
    const float pp = v0 * v1;
    float inc2 = pp;
#pragma unroll
    for (int off = 1; off < 64; off <<= 1) {
        float y = __shfl_up(inc2, off, 64);
        if (lane >= off) inc2 *= y;
    }
    if (lane == 63) s_tmp[8 + wv] = inc2;
    __syncthreads();
    if (wv == 1) inc2 *= s_tmp[8];
    __syncthreads();
    s_scan[tid] = inc2;
    __syncthreads();
    const float e = (tid == 0) ? 1.0f : s_scan[tid - 1];
    const float T0 = e, T1 = e * v0;
    const float w0 = a0 * T0, w1 = a1 * T1;

    const float4 r0 = s_rgb[src0];
    const float4 r1 = s_rgb[src1];

    const float inv_fn = 1.0f / (farv - nearv);
    const float oz0 = clampf((z0 - nearv) * inv_fn, 0.0f, 1.0f);
    const float oz1 = clampf((z1 - nearv) * inv_fn, 0.0f, 1.0f);

    float vals[6];
    vals[0] = w0 * r0.x + w1 * r1.x;
    vals[1] = w0 * r0.y + w1 * r1.y;
    vals[2] = w0 * r0.z + w1 * r1.z;
    vals[3] = w0 * r0.w + w1 * r1.w;
    vals[4] = w0 * oz0 + w1 * oz1;       // depth partial
    vals[5] = w0 + w1;                   // weights_sum partial

    // reduce 6 values over 128 threads
#pragma unroll
    for (int q = 0; q < 6; ++q) {
        float v = vals[q];
#pragma unroll
        for (int off = 32; off; off >>= 1) v += __shfl_down(v, off, 64);
        vals[q] = v;
    }
    if (lane == 0) {
#pragma unroll
        for (int q = 0; q < 6; ++q) s_tmp[wv * 8 + q] = vals[q];
    }
    __syncthreads();
    if (tid == 0) {
        const float wsum = s_tmp[5] + s_tmp[13];
        const float dep  = s_tmp[4] + s_tmp[12];
#pragma unroll
        for (int c = 0; c < 4; ++c)
            out[ray * 4 + c] = (s_tmp[c] + s_tmp[8 + c]) + (1.0f - wsum);
        out[4 * N_RAYS + ray] = dep;
        out[5 * N_RAYS + ray] = wsum;
    }
}

extern "C" void kernel_launch(void* const* d_in, const int* in_sizes, int n_in,
                              void* d_out, int out_size, void* d_ws, size_t ws_size,
                              hipStream_t stream) {
    const float* rays_o = (const float*)d_in[0];
    const float* rays_d = (const float*)d_in[1];
    const float* W1 = (const float*)d_in[2];
    const float* b1 = (const float*)d_in[3];
    const float* W2 = (const float*)d_in[4];
    const float* b2 = (const float*)d_in[5];
    const float* Wc = (const float*)d_in[6];
    const float* Wd = (const float*)d_in[7];
    const float* bc = (const float*)d_in[8];
    float* out = (float*)d_out;
    float* ws  = (float*)d_ws;

    hipLaunchKernelGGL(nerf_prep_kernel, dim3(1), dim3(128), 0, stream,
                       W2, b2, Wc, bc, ws);
    hipLaunchKernelGGL(nerf_render_kernel, dim3(N_RAYS), dim3(128), 0, stream,
                       rays_o, rays_d, W1, b1, Wd, ws, out);
}

// Round 5
// 53.673 us; speedup vs baseline: 6.4527x; 1.5257x over previous
//
#include <hip/hip_runtime.h>
#include <math.h>

#define N_RAYS 16384
#define S 128
#define U 128
#define TT 256
#define FEAT 15
#define BOUNDF 2.0f
#define MIN_NEAR 0.05f
#define RPB 4            // rays (waves) per 256-thread block

typedef float f32x2 __attribute__((ext_vector_type(2)));
typedef __fp16 h16x2 __attribute__((ext_vector_type(2)));

// ws float layout:
// [0..127]   Wf: pair-major: [(j>>1)*8 + c*2 + (j&1)] = fused W2[:,1:]@Wc for hidden j, channel c
// [128..131] bfused[c]
// [132..163] wS[j] (sigma column of W2)
// [164]      b2_0
#define WS_WF 0
#define WS_BF 128
#define WS_WS 132
#define WS_B20 164

__device__ __forceinline__ f32x2 pk_fma_vv(f32x2 a, f32x2 b, f32x2 c) {
    f32x2 d;
    asm("v_pk_fma_f32 %0, %1, %2, %3" : "=v"(d) : "v"(a), "v"(b), "v"(c));
    return d;
}
__device__ __forceinline__ f32x2 pk_fma_sv(f32x2 a, f32x2 bs, f32x2 c) {
    f32x2 d;
    asm("v_pk_fma_f32 %0, %1, %2, %3" : "=v"(d) : "v"(a), "s"(bs), "v"(c));
    return d;
}

__device__ __forceinline__ float softplus_f(float x) {
    float e = __builtin_amdgcn_exp2f(x * 1.442695041f);
    return 0.69314718056f * __builtin_amdgcn_logf(1.0f + e);
}
__device__ __forceinline__ float sigmoid_f(float x) {
    float e = __builtin_amdgcn_exp2f(x * -1.442695041f);
    return __builtin_amdgcn_rcpf(1.0f + e);
}
__device__ __forceinline__ float clampf(float x, float lo, float hi) {
    return fminf(fmaxf(x, lo), hi);
}
__device__ __forceinline__ uint2 pack_rgb(float c0, float c1, float c2, float c3) {
    h16x2 p0 = __builtin_amdgcn_cvt_pkrtz(c0, c1);
    h16x2 p1 = __builtin_amdgcn_cvt_pkrtz(c2, c3);
    uint2 r;
    r.x = __builtin_bit_cast(unsigned int, p0);
    r.y = __builtin_bit_cast(unsigned int, p1);
    return r;
}
__device__ __forceinline__ void unpack_rgb(unsigned int lo, unsigned int hi, float* c) {
    h16x2 p0 = __builtin_bit_cast(h16x2, lo);
    h16x2 p1 = __builtin_bit_cast(h16x2, hi);
    c[0] = (float)p0.x; c[1] = (float)p0.y; c[2] = (float)p1.x; c[3] = (float)p1.y;
}

extern "C" __global__ __launch_bounds__(128)
void nerf_prep_kernel(const float* __restrict__ W2, const float* __restrict__ b2,
                      const float* __restrict__ Wc, const float* __restrict__ bc,
                      float* __restrict__ ws) {
    const int t = threadIdx.x;          // 128 threads
    const int j = t >> 2, c = t & 3;
    float acc = 0.0f;
#pragma unroll
    for (int k = 0; k < FEAT; ++k) acc += W2[j * 16 + 1 + k] * Wc[k * 4 + c];
    ws[WS_WF + (j >> 1) * 8 + c * 2 + (j & 1)] = acc;
    if (t < 4) {
        float b = bc[t];
#pragma unroll
        for (int k = 0; k < FEAT; ++k) b += b2[1 + k] * Wc[k * 4 + t];
        ws[WS_BF + t] = b;
    }
    if (t < 32) ws[WS_WS + t] = W2[t * 16];
    if (t == 0) ws[WS_B20] = b2[0];
}

extern "C" __global__ __launch_bounds__(256)
void nerf_render_kernel(const float* __restrict__ rays_o,
                        const float* __restrict__ rays_d,
                        const float* __restrict__ W1, const float* __restrict__ b1,
                        const float* __restrict__ Wd,
                        const float* __restrict__ wsf,
                        float* __restrict__ out) {
    const int wv   = threadIdx.x >> 6;     // wave index in block = ray slot
    const int lane = threadIdx.x & 63;
    const int ray  = blockIdx.x * RPB + wv;

    __shared__ __align__(16) f32x2 s_A2[RPB][16];
    __shared__ __align__(16) f32x2 s_B2[RPB][16];
    __shared__ __align__(16) float s_z[RPB][TT];     // [0..127] coarse, [128..255] fine
    __shared__ __align__(16) float s_cdf[RPB][128];  // 127 used
    __shared__ __align__(16) float s_zs[RPB][TT];    // sorted z
    __shared__ __align__(16) float s_sigs[RPB][TT];  // sorted sigma
    __shared__ __align__(16) uint2 s_rgbs[RPB][TT];  // sorted rgb (4x fp16)

    // ---- ray setup (uniform per wave) ----
    const float ox = rays_o[ray * 3 + 0], oy = rays_o[ray * 3 + 1], oz = rays_o[ray * 3 + 2];
    const float dx = rays_d[ray * 3 + 0], dy = rays_d[ray * 3 + 1], dz = rays_d[ray * 3 + 2];

    auto invd = [](float d) { float dd = (fabsf(d) < 1e-9f) ? 1e-9f : d; return 1.0f / dd; };
    const float ixv = invd(dx), iyv = invd(dy), izv = invd(dz);
    const float t1x = (-BOUNDF - ox) * ixv, t2x = (BOUNDF - ox) * ixv;
    const float t1y = (-BOUNDF - oy) * iyv, t2y = (BOUNDF - oy) * iyv;
    const float t1z = (-BOUNDF - oz) * izv, t2z = (BOUNDF - oz) * izv;
    float nearv = fmaxf(fmaxf(fminf(t1x, t2x), fminf(t1y, t2y)), fminf(t1z, t2z));
    nearv = fmaxf(nearv, MIN_NEAR);
    float farv = fminf(fminf(fmaxf(t1x, t2x), fmaxf(t1y, t2y)), fmaxf(t1z, t2z));
    farv = fmaxf(farv, nearv + 1e-5f);
    const float fmn = farv - nearv;
    const float sample_dist = fmn * (1.0f / (float)S);

    // per-ray rgb bias: bfused + d @ Wd
    float rayc[4];
#pragma unroll
    for (int c = 0; c < 4; ++c)
        rayc[c] = wsf[WS_BF + c] + dx * Wd[c] + dy * Wd[4 + c] + dz * Wd[8 + c];
    const float b20 = wsf[WS_B20];

    // ---- per-ray layer-1 fold: A_j = b1_j + o.W1_j ; B_j = d.W1_j ----
    if (lane < 32) {
        const int j = lane;
        const float w0 = W1[j], w1 = W1[32 + j], w2 = W1[64 + j];
        ((float*)&s_A2[wv][0])[j] = b1[j] + ox * w0 + oy * w1 + oz * w2;
        ((float*)&s_B2[wv][0])[j] = dx * w0 + dy * w1 + dz * w2;
    }
    __syncthreads();   // barrier 1

    // ---- packed-fp32 fused MLP for two z values ----
    auto mlp2 = [&](float za, float zb, float& sga, float& sgb, uint2& ra, uint2& rb) {
        const f32x2 za2 = {za, za}, zb2 = {zb, zb};
        f32x2 aSa = {0.f, 0.f}, aSb = {0.f, 0.f};
        f32x2 a0a = {0.f, 0.f}, a1a = {0.f, 0.f}, a2a = {0.f, 0.f}, a3a = {0.f, 0.f};
        f32x2 a0b = {0.f, 0.f}, a1b = {0.f, 0.f}, a2b = {0.f, 0.f}, a3b = {0.f, 0.f};
#pragma unroll 4
        for (int t = 0; t < 16; ++t) {
            f32x2 A2 = s_A2[wv][t], B2 = s_B2[wv][t];
            f32x2 ha = pk_fma_vv(za2, B2, A2);
            f32x2 hb = pk_fma_vv(zb2, B2, A2);
            ha.x = fmaxf(ha.x, 0.f); ha.y = fmaxf(ha.y, 0.f);
            hb.x = fmaxf(hb.x, 0.f); hb.y = fmaxf(hb.y, 0.f);
            const f32x2 wsg = *(const f32x2*)(wsf + WS_WS + 2 * t);
            const f32x2* wf = (const f32x2*)(wsf + WS_WF + 8 * t);
            const f32x2 w0 = wf[0], w1 = wf[1], w2 = wf[2], w3 = wf[3];
            aSa = pk_fma_sv(ha, wsg, aSa); aSb = pk_fma_sv(hb, wsg, aSb);
            a0a = pk_fma_sv(ha, w0, a0a); a0b = pk_fma_sv(hb, w0, a0b);
            a1a = pk_fma_sv(ha, w1, a1a); a1b = pk_fma_sv(hb, w1, a1b);
            a2a = pk_fma_sv(ha, w2, a2a); a2b = pk_fma_sv(hb, w2, a2b);
            a3a = pk_fma_sv(ha, w3, a3a); a3b = pk_fma_sv(hb, w3, a3b);
        }
        sga = softplus_f(b20 + aSa.x + aSa.y);
        sgb = softplus_f(b20 + aSb.x + aSb.y);
        ra = pack_rgb(sigmoid_f(rayc[0] + a0a.x + a0a.y), sigmoid_f(rayc[1] + a1a.x + a1a.y),
                      sigmoid_f(rayc[2] + a2a.x + a2a.y), sigmoid_f(rayc[3] + a3a.x + a3a.y));
        rb = pack_rgb(sigmoid_f(rayc[0] + a0b.x + a0b.y), sigmoid_f(rayc[1] + a1b.x + a1b.y),
                      sigmoid_f(rayc[2] + a2b.x + a2b.y), sigmoid_f(rayc[3] + a3b.x + a3b.y));
    };

    // ---- coarse pass: samples 2*lane, 2*lane+1 ----
    const float stepc = 1.0f / (float)(S - 1);
    const float zc0 = nearv + fmn * ((float)(2 * lane) * stepc);
    const float zc1 = nearv + fmn * ((float)(2 * lane + 1) * stepc);
    float sgc0, sgc1; uint2 rc0, rc1;
    mlp2(zc0, zc1, sgc0, sgc1, rc0, rc1);
    s_z[wv][2 * lane] = zc0;
    s_z[wv][2 * lane + 1] = zc1;

    // ---- coarse composite weights (for PDF), pure wave ops ----
    const float znext = __shfl_down(zc0, 1, 64);      // z(2l+2)
    const float dc0 = zc1 - zc0;
    const float dc1 = (lane == 63) ? sample_dist : (znext - zc1);
    const float ec0 = __builtin_amdgcn_exp2f(dc0 * sgc0 * -1.442695041f);
    const float ec1 = __builtin_amdgcn_exp2f(dc1 * sgc1 * -1.442695041f);
    const float alc0 = 1.f - ec0, alc1 = 1.f - ec1;
    const float vc0 = ec0 + 1e-15f, vc1 = ec1 + 1e-15f;
    float incl = vc0 * vc1;
#pragma unroll
    for (int off = 1; off < 64; off <<= 1) {
        float y = __shfl_up(incl, off, 64);
        if (lane >= off) incl *= y;
    }
    float excl = __shfl_up(incl, 1, 64);
    if (lane == 0) excl = 1.f;
    const float wc0 = alc0 * excl;
    const float wc1 = alc1 * (excl * vc0);

    // pdf bins j=0..125 use w[j+1]: lane l handles bins 2l, 2l+1
    const float wnext = __shfl_down(wc0, 1, 64);      // w(2l+2)
    float p0 = wc1 + 1e-5f, p1 = wnext + 1e-5f;
    if (lane == 63) { p0 = 0.f; p1 = 0.f; }
    const float s01 = p0 + p1;
    float cinc = s01;
#pragma unroll
    for (int off = 1; off < 64; off <<= 1) {
        float y = __shfl_up(cinc, off, 64);
        if (lane >= off) cinc += y;
    }
    const float total = __shfl(cinc, 63, 64);
    const float rtot = __builtin_amdgcn_rcpf(total);
    const float cexcl = cinc - s01;
    if (lane < 63) {
        s_cdf[wv][2 * lane + 1] = (cexcl + p0) * rtot;
        s_cdf[wv][2 * lane + 2] = (cexcl + p0 + p1) * rtot;
    } else {
        s_cdf[wv][0] = 0.f;
    }
    __syncthreads();   // barrier 2: s_cdf + coarse s_z visible

    // ---- inverse-CDF fine sampling: samples 2*lane, 2*lane+1 ----
    auto fine_z = [&](float u) -> float {
        int lo = 0, hi = 127;
#pragma unroll
        for (int it = 0; it < 7; ++it) {
            int m = (lo + hi) >> 1;
            bool le = (s_cdf[wv][m] <= u);
            lo = le ? (m + 1) : lo;
            hi = le ? hi : m;
        }
        const int below = lo - 1;
        const int above = (lo > 126) ? 126 : lo;
        const float cb = s_cdf[wv][below], ca = s_cdf[wv][above];
        const float bb = 0.5f * (s_z[wv][below] + s_z[wv][below + 1]);
        const float ba = 0.5f * (s_z[wv][above] + s_z[wv][above + 1]);
        float den = ca - cb;
        if (den < 1e-5f) den = 1.0f;
        const float tt = (u - cb) * __builtin_amdgcn_rcpf(den);
        return bb + tt * (ba - bb);
    };
    const float zf0 = fine_z(((float)(2 * lane) + 0.5f) * (1.0f / 128.f));
    const float zf1 = fine_z(((float)(2 * lane) + 1.5f) * (1.0f / 128.f));
    float sgf0, sgf1; uint2 rf0, rf1;
    mlp2(zf0, zf1, sgf0, sgf1, rf0, rf1);
    s_z[wv][128 + 2 * lane] = zf0;
    s_z[wv][129 + 2 * lane] = zf1;
    __syncthreads();   // barrier 3: fine s_z visible

    // ---- stable merge of two sorted 128-lists, write sorted triples ----
    // Guarded fixed-iteration binary search: insertion point can be 128
    // (e.g. the coarse far sample exceeds ALL fine samples); the guard
    // prevents the converged state lo==hi==128 from probing a[128] OOB.
    const float* zcarr = &s_z[wv][0];
    const float* zfarr = &s_z[wv][128];
    auto cnt_lt = [&](const float* a, float z) -> int {   // #{a[k] < z}, n=128
        int lo = 0, hi = 128;
#pragma unroll
        for (int it = 0; it < 8; ++it) {
            int m = (lo + hi) >> 1;
            bool b = (m < 128) && (a[m] < z);
            lo = b ? (m + 1) : lo;
            hi = b ? hi : m;
        }
        return lo;
    };
    auto cnt_le = [&](const float* a, float z) -> int {   // #{a[k] <= z}, n=128
        int lo = 0, hi = 128;
#pragma unroll
        for (int it = 0; it < 8; ++it) {
            int m = (lo + hi) >> 1;
            bool b = (m < 128) && (a[m] <= z);
            lo = b ? (m + 1) : lo;
            hi = b ? hi : m;
        }
        return lo;
    };
    {
        const int dA = 2 * lane + cnt_lt(zfarr, zc0);
        const int dB = 2 * lane + 1 + cnt_lt(zfarr, zc1);
        s_zs[wv][dA] = zc0; s_sigs[wv][dA] = sgc0; s_rgbs[wv][dA] = rc0;
        s_zs[wv][dB] = zc1; s_sigs[wv][dB] = sgc1; s_rgbs[wv][dB] = rc1;
    }
    {
        const int dA = 2 * lane + cnt_le(zcarr, zf0);
        const int dB = 2 * lane + 1 + cnt_le(zcarr, zf1);
        s_zs[wv][dA] = zf0; s_sigs[wv][dA] = sgf0; s_rgbs[wv][dA] = rf0;
        s_zs[wv][dB] = zf1; s_sigs[wv][dB] = sgf1; s_rgbs[wv][dB] = rf1;
    }
    __syncthreads();   // barrier 4: sorted arrays visible

    // ---- final compositing: 4 sorted samples per lane ----
    const float4 z4 = *(const float4*)&s_zs[wv][4 * lane];
    const float4 g4 = *(const float4*)&s_sigs[wv][4 * lane];
    const uint4 rp01 = *(const uint4*)&s_rgbs[wv][4 * lane];
    const uint4 rp23 = *(const uint4*)&s_rgbs[wv][4 * lane + 2];

    const float znx = __shfl_down(z4.x, 1, 64);
    const float dd0 = z4.y - z4.x;
    const float dd1 = z4.z - z4.y;
    const float dd2 = z4.w - z4.z;
    const float dd3 = (lane == 63) ? sample_dist : (znx - z4.w);

    const float e0 = __builtin_amdgcn_exp2f(dd0 * g4.x * -1.442695041f);
    const float e1 = __builtin_amdgcn_exp2f(dd1 * g4.y * -1.442695041f);
    const float e2 = __builtin_amdgcn_exp2f(dd2 * g4.z * -1.442695041f);
    const float e3 = __builtin_amdgcn_exp2f(dd3 * g4.w * -1.442695041f);
    const float al0 = 1.f - e0, al1 = 1.f - e1, al2 = 1.f - e2, al3 = 1.f - e3;
    const float v0 = e0 + 1e-15f, v1 = e1 + 1e-15f, v2 = e2 + 1e-15f, v3 = e3 + 1e-15f;

    float incl2 = v0 * v1 * v2 * v3;
#pragma unroll
    for (int off = 1; off < 64; off <<= 1) {
        float y = __shfl_up(incl2, off, 64);
        if (lane >= off) incl2 *= y;
    }
    float T0 = __shfl_up(incl2, 1, 64);
    if (lane == 0) T0 = 1.f;
    const float T1 = T0 * v0, T2 = T1 * v1, T3 = T2 * v2;
    const float w0 = al0 * T0, w1 = al1 * T1, w2 = al2 * T2, w3 = al3 * T3;

    const float inv_fn = 1.0f / fmn;
    const float oz0 = clampf((z4.x - nearv) * inv_fn, 0.f, 1.f);
    const float oz1 = clampf((z4.y - nearv) * inv_fn, 0.f, 1.f);
    const float oz2 = clampf((z4.z - nearv) * inv_fn, 0.f, 1.f);
    const float oz3 = clampf((z4.w - nearv) * inv_fn, 0.f, 1.f);

    float r0[4], r1[4], r2[4], r3[4];
    unpack_rgb(rp01.x, rp01.y, r0);
    unpack_rgb(rp01.z, rp01.w, r1);
    unpack_rgb(rp23.x, rp23.y, r2);
    unpack_rgb(rp23.z, rp23.w, r3);

    float vals[6];
#pragma unroll
    for (int c = 0; c < 4; ++c)
        vals[c] = w0 * r0[c] + w1 * r1[c] + w2 * r2[c] + w3 * r3[c];
    vals[4] = w0 * oz0 + w1 * oz1 + w2 * oz2 + w3 * oz3;
    vals[5] = w0 + w1 + w2 + w3;

#pragma unroll
    for (int q = 0; q < 6; ++q) {
        float v = vals[q];
#pragma unroll
        for (int off = 32; off; off >>= 1) v += __shfl_down(v, off, 64);
        vals[q] = v;
    }
    if (lane == 0) {
        const float wsum = vals[5];
#pragma unroll
        for (int c = 0; c < 4; ++c)
            out[ray * 4 + c] = vals[c] + (1.0f - wsum);
        out[4 * N_RAYS + ray] = vals[4];
        out[5 * N_RAYS + ray] = wsum;
    }
}

extern "C" void kernel_launch(void* const* d_in, const int* in_sizes, int n_in,
                              void* d_out, int out_size, void* d_ws, size_t ws_size,
                              hipStream_t stream) {
    const float* rays_o = (const float*)d_in[0];
    const float* rays_d = (const float*)d_in[1];
    const float* W1 = (const float*)d_in[2];
    const float* b1 = (const float*)d_in[3];
    const float* W2 = (const float*)d_in[4];
    const float* b2 = (const float*)d_in[5];
    const float* Wc = (const float*)d_in[6];
    const float* Wd = (const float*)d_in[7];
    const float* bc = (const float*)d_in[8];
    float* out = (float*)d_out;
    float* ws  = (float*)d_ws;

    hipLaunchKernelGGL(nerf_prep_kernel, dim3(1), dim3(128), 0, stream,
                       W2, b2, Wc, bc, ws);
    hipLaunchKernelGGL(nerf_render_kernel, dim3(N_RAYS / RPB), dim3(256), 0, stream,
                       rays_o, rays_d, W1, b1, Wd, ws, out);
}

// Round 6
// 46.624 us; speedup vs baseline: 7.4283x; 1.1512x over previous
//
#include <hip/hip_runtime.h>
#include <math.h>

#define N_RAYS 16384
#define S 128
#define TT 256
#define FEAT 15
#define BOUNDF 2.0f
#define MIN_NEAR 0.05f

typedef float f32x2 __attribute__((ext_vector_type(2)));
typedef __fp16 h16x2 __attribute__((ext_vector_type(2)));

// ws float layout:
// [0..127]   Wf pair-major: [(j>>1)*8 + c*2 + (j&1)] = (W2[:,1:]@Wc)[j][c]
// [128..131] bfused[c]
// [132..163] wS[j] (sigma column of W2)
// [164]      b2_0
#define WS_WF 0
#define WS_BF 128
#define WS_WS 132
#define WS_B20 164

__device__ __forceinline__ f32x2 pk_fma_vv(f32x2 a, f32x2 b, f32x2 c) {
    f32x2 d;
    asm("v_pk_fma_f32 %0, %1, %2, %3" : "=v"(d) : "v"(a), "v"(b), "v"(c));
    return d;
}
__device__ __forceinline__ f32x2 pk_fma_sv(f32x2 a, f32x2 bs, f32x2 c) {
    f32x2 d;
    asm("v_pk_fma_f32 %0, %1, %2, %3" : "=v"(d) : "v"(a), "s"(bs), "v"(c));
    return d;
}

__device__ __forceinline__ float softplus_f(float x) {
    float e = __builtin_amdgcn_exp2f(x * 1.442695041f);
    return 0.69314718056f * __builtin_amdgcn_logf(1.0f + e);   // logf builtin = log2
}
__device__ __forceinline__ float sigmoid_f(float x) {
    float e = __builtin_amdgcn_exp2f(x * -1.442695041f);
    return __builtin_amdgcn_rcpf(1.0f + e);
}
__device__ __forceinline__ float clampf(float x, float lo, float hi) {
    return fminf(fmaxf(x, lo), hi);
}
__device__ __forceinline__ uint2 pack_rgb(float c0, float c1, float c2, float c3) {
    h16x2 p0 = __builtin_amdgcn_cvt_pkrtz(c0, c1);
    h16x2 p1 = __builtin_amdgcn_cvt_pkrtz(c2, c3);
    uint2 r;
    r.x = __builtin_bit_cast(unsigned int, p0);
    r.y = __builtin_bit_cast(unsigned int, p1);
    return r;
}
__device__ __forceinline__ void unpack_rgb(unsigned int lo, unsigned int hi, float* c) {
    h16x2 p0 = __builtin_bit_cast(h16x2, lo);
    h16x2 p1 = __builtin_bit_cast(h16x2, hi);
    c[0] = (float)p0.x; c[1] = (float)p0.y; c[2] = (float)p1.x; c[3] = (float)p1.y;
}

extern "C" __global__ __launch_bounds__(128)
void nerf_prep_kernel(const float* __restrict__ W2, const float* __restrict__ b2,
                      const float* __restrict__ Wc, const float* __restrict__ bc,
                      float* __restrict__ ws) {
    const int t = threadIdx.x;          // 128 threads
    const int j = t >> 2, c = t & 3;
    float acc = 0.0f;
#pragma unroll
    for (int k = 0; k < FEAT; ++k) acc += W2[j * 16 + 1 + k] * Wc[k * 4 + c];
    ws[WS_WF + (j >> 1) * 8 + c * 2 + (j & 1)] = acc;
    if (t < 4) {
        float b = bc[t];
#pragma unroll
        for (int k = 0; k < FEAT; ++k) b += b2[1 + k] * Wc[k * 4 + t];
        ws[WS_BF + t] = b;
    }
    if (t < 32) ws[WS_WS + t] = W2[t * 16];
    if (t == 0) ws[WS_B20] = b2[0];
}

extern "C" __global__ __launch_bounds__(64)
void nerf_render_kernel(const float* __restrict__ rays_o,
                        const float* __restrict__ rays_d,
                        const float* __restrict__ W1, const float* __restrict__ b1,
                        const float* __restrict__ Wd,
                        const float* __restrict__ wsf,
                        float* __restrict__ out) {
    const int lane = threadIdx.x;      // one 64-lane wave per ray
    const int ray  = blockIdx.x;

    __shared__ __align__(16) float4 s_AB[16];     // {A2t.x,A2t.y,B2t.x,B2t.y}
    __shared__ __align__(16) float  s_zs[TT];     // [0..127] coarse z; later: sorted z
    __shared__ __align__(16) float  s_cdf[128];   // 127 used
    __shared__ int   s_histU[129];
    __shared__ int   s_histM[129];
    __shared__ __align__(16) float  s_sigs[TT];   // sorted sigma
    __shared__ __align__(16) uint2  s_rgbs[TT];   // sorted rgb (4x fp16)

    // ---- ray setup (uniform per wave) ----
    const float ox = rays_o[ray * 3 + 0], oy = rays_o[ray * 3 + 1], oz = rays_o[ray * 3 + 2];
    const float dx = rays_d[ray * 3 + 0], dy = rays_d[ray * 3 + 1], dz = rays_d[ray * 3 + 2];

    auto invd = [](float d) { float dd = (fabsf(d) < 1e-9f) ? 1e-9f : d; return 1.0f / dd; };
    const float ixv = invd(dx), iyv = invd(dy), izv = invd(dz);
    const float t1x = (-BOUNDF - ox) * ixv, t2x = (BOUNDF - ox) * ixv;
    const float t1y = (-BOUNDF - oy) * iyv, t2y = (BOUNDF - oy) * iyv;
    const float t1z = (-BOUNDF - oz) * izv, t2z = (BOUNDF - oz) * izv;
    float nearv = fmaxf(fmaxf(fminf(t1x, t2x), fminf(t1y, t2y)), fminf(t1z, t2z));
    nearv = fmaxf(nearv, MIN_NEAR);
    float farv = fminf(fminf(fmaxf(t1x, t2x), fmaxf(t1y, t2y)), fmaxf(t1z, t2z));
    farv = fmaxf(farv, nearv + 1e-5f);
    const float fmn = farv - nearv;
    const float sample_dist = fmn * (1.0f / (float)S);

    // zero histograms (used later; ordered by barrier 1)
    s_histU[lane] = 0; s_histU[64 + lane] = 0;
    s_histM[lane] = 0; s_histM[64 + lane] = 0;
    if (lane == 0) { s_histU[128] = 0; s_histM[128] = 0; }

    // per-ray rgb bias: bfused + d @ Wd
    float rayc[4];
#pragma unroll
    for (int c = 0; c < 4; ++c)
        rayc[c] = wsf[WS_BF + c] + dx * Wd[c] + dy * Wd[4 + c] + dz * Wd[8 + c];
    const float b20 = wsf[WS_B20];

    // ---- per-ray layer-1 fold: A_j = b1_j + o.W1_j ; B_j = d.W1_j (interleaved) ----
    if (lane < 32) {
        const int j = lane;
        const float w0 = W1[j], w1 = W1[32 + j], w2 = W1[64 + j];
        ((float*)&s_AB[j >> 1])[(j & 1)]     = b1[j] + ox * w0 + oy * w1 + oz * w2;
        ((float*)&s_AB[j >> 1])[2 + (j & 1)] = dx * w0 + dy * w1 + dz * w2;
    }
    __syncthreads();   // b1 (single-wave: just a waitcnt)

    // ---- packed-fp32 fused MLP for two z values ----
    auto mlp2 = [&](float za, float zb, float& sga, float& sgb, uint2& ra, uint2& rb) {
        const f32x2 za2 = {za, za}, zb2 = {zb, zb};
        const f32x2 zero2 = {0.f, 0.f};
        f32x2 aSa = zero2, aSb = zero2;
        f32x2 a0a = zero2, a1a = zero2, a2a = zero2, a3a = zero2;
        f32x2 a0b = zero2, a1b = zero2, a2b = zero2, a3b = zero2;
#pragma unroll 4
        for (int t = 0; t < 16; ++t) {
            const float4 ab = s_AB[t];
            const f32x2 A2 = {ab.x, ab.y}, B2 = {ab.z, ab.w};
            f32x2 ha = pk_fma_vv(za2, B2, A2);
            f32x2 hb = pk_fma_vv(zb2, B2, A2);
            ha = __builtin_elementwise_max(ha, zero2);
            hb = __builtin_elementwise_max(hb, zero2);
            const f32x2 wsg = *(const f32x2*)(wsf + WS_WS + 2 * t);
            const f32x2* wf = (const f32x2*)(wsf + WS_WF + 8 * t);
            const f32x2 w0 = wf[0], w1 = wf[1], w2 = wf[2], w3 = wf[3];
            aSa = pk_fma_sv(ha, wsg, aSa); aSb = pk_fma_sv(hb, wsg, aSb);
            a0a = pk_fma_sv(ha, w0, a0a); a0b = pk_fma_sv(hb, w0, a0b);
            a1a = pk_fma_sv(ha, w1, a1a); a1b = pk_fma_sv(hb, w1, a1b);
            a2a = pk_fma_sv(ha, w2, a2a); a2b = pk_fma_sv(hb, w2, a2b);
            a3a = pk_fma_sv(ha, w3, a3a); a3b = pk_fma_sv(hb, w3, a3b);
        }
        sga = softplus_f(b20 + aSa.x + aSa.y);
        sgb = softplus_f(b20 + aSb.x + aSb.y);
        ra = pack_rgb(sigmoid_f(rayc[0] + a0a.x + a0a.y), sigmoid_f(rayc[1] + a1a.x + a1a.y),
                      sigmoid_f(rayc[2] + a2a.x + a2a.y), sigmoid_f(rayc[3] + a3a.x + a3a.y));
        rb = pack_rgb(sigmoid_f(rayc[0] + a0b.x + a0b.y), sigmoid_f(rayc[1] + a1b.x + a1b.y),
                      sigmoid_f(rayc[2] + a2b.x + a2b.y), sigmoid_f(rayc[3] + a3b.x + a3b.y));
    };

    // ---- coarse pass: samples 2*lane, 2*lane+1 ----
    const float stepc = 1.0f / (float)(S - 1);
    const float zc0 = nearv + fmn * ((float)(2 * lane) * stepc);
    const float zc1 = nearv + fmn * ((float)(2 * lane + 1) * stepc);
    float sgc0, sgc1; uint2 rc0, rc1;
    mlp2(zc0, zc1, sgc0, sgc1, rc0, rc1);
    s_zs[2 * lane] = zc0;
    s_zs[2 * lane + 1] = zc1;

    // ---- coarse composite weights (for PDF), pure wave ops ----
    const float znext = __shfl_down(zc0, 1, 64);      // z(2l+2)
    const float dc0 = zc1 - zc0;
    const float dc1 = (lane == 63) ? sample_dist : (znext - zc1);
    const float ec0 = __builtin_amdgcn_exp2f(dc0 * sgc0 * -1.442695041f);
    const float ec1 = __builtin_amdgcn_exp2f(dc1 * sgc1 * -1.442695041f);
    const float alc0 = 1.f - ec0, alc1 = 1.f - ec1;
    const float vc0 = ec0 + 1e-15f, vc1 = ec1 + 1e-15f;
    float incl = vc0 * vc1;
#pragma unroll
    for (int off = 1; off < 64; off <<= 1) {
        float y = __shfl_up(incl, off, 64);
        if (lane >= off) incl *= y;
    }
    float excl = __shfl_up(incl, 1, 64);
    if (lane == 0) excl = 1.f;
    const float wc0 = alc0 * excl;
    const float wc1 = alc1 * (excl * vc0);

    // pdf bins j=0..125 use w[j+1]: lane l handles bins 2l, 2l+1
    const float wnext = __shfl_down(wc0, 1, 64);      // w(2l+2)
    float p0 = wc1 + 1e-5f, p1 = wnext + 1e-5f;
    if (lane == 63) { p0 = 0.f; p1 = 0.f; }
    const float s01 = p0 + p1;
    float cinc = s01;
#pragma unroll
    for (int off = 1; off < 64; off <<= 1) {
        float y = __shfl_up(cinc, off, 64);
        if (lane >= off) cinc += y;
    }
    const float total = __shfl(cinc, 63, 64);
    const float rtot = __builtin_amdgcn_rcpf(total);
    const float cexcl = cinc - s01;
    if (lane < 63) {
        const float cdfA = (cexcl + p0) * rtot;        // index 2l+1
        const float cdfB = (cexcl + p0 + p1) * rtot;   // index 2l+2
        s_cdf[2 * lane + 1] = cdfA;
        s_cdf[2 * lane + 2] = cdfB;
        // cnt_m = #{k: u_k < cdf_m}, u_k = (k+0.5)/128  (closed form)
        int cA = (int)ceilf(fmaf(128.f, cdfA, -0.5f));
        int cB = (int)ceilf(fmaf(128.f, cdfB, -0.5f));
        cA = min(max(cA, 0), 128); cB = min(max(cB, 0), 128);
        atomicAdd(&s_histU[cA], 1);
        atomicAdd(&s_histU[cB], 1);
    } else {
        s_cdf[0] = 0.f;
        atomicAdd(&s_histU[0], 1);   // m = 0, cdf_0 = 0 -> cnt = 0
    }
    __syncthreads();   // b2

    // ---- inds_k = #{m: cnt_m <= k} via histogram prefix (replaces binary search) ----
    const int2 hu = *(const int2*)&s_histU[2 * lane];
    const int hs = hu.x + hu.y;
    int hscan = hs;
#pragma unroll
    for (int off = 1; off < 64; off <<= 1) {
        int y = __shfl_up(hscan, off, 64);
        if (lane >= off) hscan += y;
    }
    const int hexcl = hscan - hs;
    const int indsA = hexcl + hu.x;     // for u at k=2l
    const int indsB = hexcl + hs;       // for u at k=2l+1

    auto lerp_z = [&](int inds, float u) -> float {
        const int below = inds - 1;
        const int above = min(inds, 126);
        const float cb = s_cdf[below], ca = s_cdf[above];
        const float bb = 0.5f * (s_zs[below] + s_zs[below + 1]);
        const float ba = 0.5f * (s_zs[above] + s_zs[above + 1]);
        float den = ca - cb;
        if (den < 1e-5f) den = 1.0f;
        const float t = (u - cb) * __builtin_amdgcn_rcpf(den);
        return bb + t * (ba - bb);
    };
    const float zf0 = lerp_z(indsA, ((float)(2 * lane) + 0.5f) * (1.0f / 128.f));
    const float zf1 = lerp_z(indsB, ((float)(2 * lane) + 1.5f) * (1.0f / 128.f));

    float sgf0, sgf1; uint2 rf0, rf1;
    mlp2(zf0, zf1, sgf0, sgf1, rf0, rf1);

    // rank of fine in coarse: r = #{i: zc_i <= zf} (closed form, coarse grid uniform)
    const float inv_stepz = 127.0f / fmn;
    int r0 = (int)floorf((zf0 - nearv) * inv_stepz) + 1;
    int r1 = (int)floorf((zf1 - nearv) * inv_stepz) + 1;
    r0 = min(max(r0, 0), 128); r1 = min(max(r1, 0), 128);
    atomicAdd(&s_histM[r0], 1);
    atomicAdd(&s_histM[r1], 1);
    __syncthreads();   // b3

    // ---- g(j) = #{k: r_k <= j} via histogram prefix; scatter sorted triples ----
    const int2 hm = *(const int2*)&s_histM[2 * lane];
    const int ms = hm.x + hm.y;
    int mscan = ms;
#pragma unroll
    for (int off = 1; off < 64; off <<= 1) {
        int y = __shfl_up(mscan, off, 64);
        if (lane >= off) mscan += y;
    }
    const int mexcl = mscan - ms;
    const int dC0 = 2 * lane + (mexcl + hm.x);
    const int dC1 = 2 * lane + 1 + (mexcl + ms);
    const int dF0 = 2 * lane + r0;
    const int dF1 = 2 * lane + 1 + r1;

    s_zs[dC0] = zc0; s_sigs[dC0] = sgc0; s_rgbs[dC0] = rc0;
    s_zs[dC1] = zc1; s_sigs[dC1] = sgc1; s_rgbs[dC1] = rc1;
    s_zs[dF0] = zf0; s_sigs[dF0] = sgf0; s_rgbs[dF0] = rf0;
    s_zs[dF1] = zf1; s_sigs[dF1] = sgf1; s_rgbs[dF1] = rf1;
    __syncthreads();   // b4

    // ---- final compositing: 4 sorted samples per lane ----
    const float4 z4 = *(const float4*)&s_zs[4 * lane];
    const float4 g4 = *(const float4*)&s_sigs[4 * lane];
    const uint4 rp01 = *(const uint4*)&s_rgbs[4 * lane];
    const uint4 rp23 = *(const uint4*)&s_rgbs[4 * lane + 2];

    const float znx = __shfl_down(z4.x, 1, 64);
    const float dd0 = z4.y - z4.x;
    const float dd1 = z4.z - z4.y;
    const float dd2 = z4.w - z4.z;
    const float dd3 = (lane == 63) ? sample_dist : (znx - z4.w);

    const float e0 = __builtin_amdgcn_exp2f(dd0 * g4.x * -1.442695041f);
    const float e1 = __builtin_amdgcn_exp2f(dd1 * g4.y * -1.442695041f);
    const float e2 = __builtin_amdgcn_exp2f(dd2 * g4.z * -1.442695041f);
    const float e3 = __builtin_amdgcn_exp2f(dd3 * g4.w * -1.442695041f);
    const float al0 = 1.f - e0, al1 = 1.f - e1, al2 = 1.f - e2, al3 = 1.f - e3;
    const float v0 = e0 + 1e-15f, v1 = e1 + 1e-15f, v2 = e2 + 1e-15f, v3 = e3 + 1e-15f;

    float incl2 = v0 * v1 * v2 * v3;
#pragma unroll
    for (int off = 1; off < 64; off <<= 1) {
        float y = __shfl_up(incl2, off, 64);
        if (lane >= off) incl2 *= y;
    }
    float T0 = __shfl_up(incl2, 1, 64);
    if (lane == 0) T0 = 1.f;
    const float T1 = T0 * v0, T2 = T1 * v1, T3 = T2 * v2;
    const float w0 = al0 * T0, w1 = al1 * T1, w2 = al2 * T2, w3 = al3 * T3;

    const float inv_fn = 1.0f / fmn;
    const float oz0 = clampf((z4.x - nearv) * inv_fn, 0.f, 1.f);
    const float oz1 = clampf((z4.y - nearv) * inv_fn, 0.f, 1.f);
    const float oz2 = clampf((z4.z - nearv) * inv_fn, 0.f, 1.f);
    const float oz3 = clampf((z4.w - nearv) * inv_fn, 0.f, 1.f);

    float r0c[4], r1c[4], r2c[4], r3c[4];
    unpack_rgb(rp01.x, rp01.y, r0c);
    unpack_rgb(rp01.z, rp01.w, r1c);
    unpack_rgb(rp23.x, rp23.y, r2c);
    unpack_rgb(rp23.z, rp23.w, r3c);

    float vals[6];
#pragma unroll
    for (int c = 0; c < 4; ++c)
        vals[c] = w0 * r0c[c] + w1 * r1c[c] + w2 * r2c[c] + w3 * r3c[c];
    vals[4] = w0 * oz0 + w1 * oz1 + w2 * oz2 + w3 * oz3;
    vals[5] = w0 + w1 + w2 + w3;

#pragma unroll
    for (int q = 0; q < 6; ++q) {
        float v = vals[q];
#pragma unroll
        for (int off = 32; off; off >>= 1) v += __shfl_down(v, off, 64);
        vals[q] = v;
    }
    if (lane == 0) {
        const float wsum = vals[5];
#pragma unroll
        for (int c = 0; c < 4; ++c)
            out[ray * 4 + c] = vals[c] + (1.0f - wsum);
        out[4 * N_RAYS + ray] = vals[4];
        out[5 * N_RAYS + ray] = wsum;
    }
}

extern "C" void kernel_launch(void* const* d_in, const int* in_sizes, int n_in,
                              void* d_out, int out_size, void* d_ws, size_t ws_size,
                              hipStream_t stream) {
    const float* rays_o = (const float*)d_in[0];
    const float* rays_d = (const float*)d_in[1];
    const float* W1 = (const float*)d_in[2];
    const float* b1 = (const float*)d_in[3];
    const float* W2 = (const float*)d_in[4];
    const float* b2 = (const float*)d_in[5];
    const float* Wc = (const float*)d_in[6];
    const float* Wd = (const float*)d_in[7];
    const float* bc = (const float*)d_in[8];
    float* out = (float*)d_out;
    float* ws  = (float*)d_ws;

    hipLaunchKernelGGL(nerf_prep_kernel, dim3(1), dim3(128), 0, stream,
                       W2, b2, Wc, bc, ws);
    hipLaunchKernelGGL(nerf_render_kernel, dim3(N_RAYS), dim3(64), 0, stream,
                       rays_o, rays_d, W1, b1, Wd, ws, out);
}

// Round 8
// 46.550 us; speedup vs baseline: 7.4401x; 1.0016x over previous
//
#include <hip/hip_runtime.h>
#include <math.h>

#define N_RAYS 16384
#define S 128
#define FEAT 15
#define BOUNDF 2.0f
#define MIN_NEAR 0.05f
#define RPB 4              // rays (waves) per 256-thread block
#define PRW 1216           // per-ray LDS words (4864 B)

// per-ray LDS word offsets
#define O_AB   0           // 16 x float4 interleaved {A0,A1,B0,B1}
#define O_CDF  64          // 128 f32
#define O_ZS   192         // 256 f32, il4 layout
#define O_SIG  448         // 256 f32, il4
#define O_RGB  704         // 256 uint2, il4 (512 words)
#define O_HU   704         // 129 int (aliases rgb; consumed before rgb written)
#define O_HM   836         // 129 int (aliases rgb)

typedef float f32x2 __attribute__((ext_vector_type(2)));
typedef __fp16 h16x2 __attribute__((ext_vector_type(2)));

// ws float layout:
// [0..127]   Wf pair-major: [(j>>1)*8 + c*2 + (j&1)] = (W2[:,1:]@Wc)[j][c]
// [128..131] bfused[c]  [132..163] wS[j]  [164] b2_0
#define WS_WF 0
#define WS_BF 128
#define WS_WS 132
#define WS_B20 164

__device__ __forceinline__ f32x2 pk_fma_vv(f32x2 a, f32x2 b, f32x2 c) {
    f32x2 d;
    asm("v_pk_fma_f32 %0, %1, %2, %3" : "=v"(d) : "v"(a), "v"(b), "v"(c));
    return d;
}
__device__ __forceinline__ f32x2 pk_fma_sv(f32x2 a, f32x2 bs, f32x2 c) {
    f32x2 d;
    asm("v_pk_fma_f32 %0, %1, %2, %3" : "=v"(d) : "v"(a), "s"(bs), "v"(c));
    return d;
}

__device__ __forceinline__ float softplus_f(float x) {
    float e = __builtin_amdgcn_exp2f(x * 1.442695041f);
    return 0.69314718056f * __builtin_amdgcn_logf(1.0f + e);
}
__device__ __forceinline__ float sigmoid_f(float x) {
    float e = __builtin_amdgcn_exp2f(x * -1.442695041f);
    return __builtin_amdgcn_rcpf(1.0f + e);
}
__device__ __forceinline__ float clampf(float x, float lo, float hi) {
    return fminf(fmaxf(x, lo), hi);
}
__device__ __forceinline__ uint2 pack_rgb(float c0, float c1, float c2, float c3) {
    h16x2 p0 = __builtin_amdgcn_cvt_pkrtz(c0, c1);
    h16x2 p1 = __builtin_amdgcn_cvt_pkrtz(c2, c3);
    uint2 r;
    r.x = __builtin_bit_cast(unsigned int, p0);
    r.y = __builtin_bit_cast(unsigned int, p1);
    return r;
}
__device__ __forceinline__ void unpack_rgb(unsigned int lo, unsigned int hi, float* c) {
    h16x2 p0 = __builtin_bit_cast(h16x2, lo);
    h16x2 p1 = __builtin_bit_cast(h16x2, hi);
    c[0] = (float)p0.x; c[1] = (float)p0.y; c[2] = (float)p1.x; c[3] = (float)p1.y;
}

// ---- DPP wave64 inclusive scans (gfx9 pattern), pure VALU ----
// ctrl/rmask must be literal constants -> template parameters.
template<int CTRL, int RMASK>
__device__ __forceinline__ float dppf(float old, float v) {
    int r = __builtin_amdgcn_update_dpp(__builtin_bit_cast(int, old),
                                        __builtin_bit_cast(int, v),
                                        CTRL, RMASK, 0xf, false);
    return __builtin_bit_cast(float, r);
}
template<int CTRL, int RMASK>
__device__ __forceinline__ int dppi(int old, int v) {
    return __builtin_amdgcn_update_dpp(old, v, CTRL, RMASK, 0xf, false);
}

__device__ __forceinline__ float scan_mul_f(float v) {
    v *= dppf<0x111, 0xf>(1.0f, v);   // row_shr:1
    v *= dppf<0x112, 0xf>(1.0f, v);   // row_shr:2
    v *= dppf<0x114, 0xf>(1.0f, v);   // row_shr:4
    v *= dppf<0x118, 0xf>(1.0f, v);   // row_shr:8
    v *= dppf<0x142, 0xa>(1.0f, v);   // row_bcast:15 -> rows 1,3
    v *= dppf<0x143, 0xc>(1.0f, v);   // row_bcast:31 -> rows 2,3
    return v;
}
__device__ __forceinline__ float scan_add_f(float v) {
    v += dppf<0x111, 0xf>(0.0f, v);
    v += dppf<0x112, 0xf>(0.0f, v);
    v += dppf<0x114, 0xf>(0.0f, v);
    v += dppf<0x118, 0xf>(0.0f, v);
    v += dppf<0x142, 0xa>(0.0f, v);
    v += dppf<0x143, 0xc>(0.0f, v);
    return v;
}
__device__ __forceinline__ int scan_add_i(int v) {
    v += dppi<0x111, 0xf>(0, v);
    v += dppi<0x112, 0xf>(0, v);
    v += dppi<0x114, 0xf>(0, v);
    v += dppi<0x118, 0xf>(0, v);
    v += dppi<0x142, 0xa>(0, v);
    v += dppi<0x143, 0xc>(0, v);
    return v;
}

extern "C" __global__ __launch_bounds__(128)
void nerf_prep_kernel(const float* __restrict__ W2, const float* __restrict__ b2,
                      const float* __restrict__ Wc, const float* __restrict__ bc,
                      float* __restrict__ ws) {
    const int t = threadIdx.x;
    const int j = t >> 2, c = t & 3;
    float acc = 0.0f;
#pragma unroll
    for (int k = 0; k < FEAT; ++k) acc += W2[j * 16 + 1 + k] * Wc[k * 4 + c];
    ws[WS_WF + (j >> 1) * 8 + c * 2 + (j & 1)] = acc;
    if (t < 4) {
        float b = bc[t];
#pragma unroll
        for (int k = 0; k < FEAT; ++k) b += b2[1 + k] * Wc[k * 4 + t];
        ws[WS_BF + t] = b;
    }
    if (t < 32) ws[WS_WS + t] = W2[t * 16];
    if (t == 0) ws[WS_B20] = b2[0];
}

extern "C" __global__ __launch_bounds__(256)
void nerf_render_kernel(const float* __restrict__ rays_o,
                        const float* __restrict__ rays_d,
                        const float* __restrict__ W1, const float* __restrict__ b1,
                        const float* __restrict__ Wd,
                        const float* __restrict__ wsf,
                        float* __restrict__ out) {
    const int wv   = threadIdx.x >> 6;
    const int lane = threadIdx.x & 63;
    const int ray  = blockIdx.x * RPB + wv;

    __shared__ __align__(16) float smem[RPB][PRW];
    float*  base  = &smem[wv][0];
    float4* sAB   = (float4*)(base + O_AB);
    float*  sCdf  = base + O_CDF;
    float*  sZ    = base + O_ZS;
    float*  sSig  = base + O_SIG;
    uint2*  sRgb  = (uint2*)(base + O_RGB);
    int*    sHU   = (int*)(base + O_HU);
    int*    sHM   = (int*)(base + O_HM);

    // ---- ray setup (uniform per wave) ----
    const float ox = rays_o[ray * 3 + 0], oy = rays_o[ray * 3 + 1], oz = rays_o[ray * 3 + 2];
    const float dx = rays_d[ray * 3 + 0], dy = rays_d[ray * 3 + 1], dz = rays_d[ray * 3 + 2];

    auto invd = [](float d) { float dd = (fabsf(d) < 1e-9f) ? 1e-9f : d; return 1.0f / dd; };
    const float ixv = invd(dx), iyv = invd(dy), izv = invd(dz);
    const float t1x = (-BOUNDF - ox) * ixv, t2x = (BOUNDF - ox) * ixv;
    const float t1y = (-BOUNDF - oy) * iyv, t2y = (BOUNDF - oy) * iyv;
    const float t1z = (-BOUNDF - oz) * izv, t2z = (BOUNDF - oz) * izv;
    float nearv = fmaxf(fmaxf(fminf(t1x, t2x), fminf(t1y, t2y)), fminf(t1z, t2z));
    nearv = fmaxf(nearv, MIN_NEAR);
    float farv = fminf(fminf(fmaxf(t1x, t2x), fmaxf(t1y, t2y)), fmaxf(t1z, t2z));
    farv = fmaxf(farv, nearv + 1e-5f);
    const float fmn = farv - nearv;
    const float sample_dist = fmn * (1.0f / (float)S);
    const float dstep = fmn * (1.0f / 127.0f);     // uniform coarse delta

    // zero histograms
    sHU[lane] = 0; sHU[64 + lane] = 0;
    sHM[lane] = 0; sHM[64 + lane] = 0;
    if (lane == 0) { sHU[128] = 0; sHM[128] = 0; }
    __builtin_amdgcn_wave_barrier();

    // per-ray rgb bias: bfused + d @ Wd
    float rayc[4];
#pragma unroll
    for (int c = 0; c < 4; ++c)
        rayc[c] = wsf[WS_BF + c] + dx * Wd[c] + dy * Wd[4 + c] + dz * Wd[8 + c];
    const float b20 = wsf[WS_B20];

    // ---- per-ray layer-1 fold: A_j = b1_j + o.W1_j ; B_j = d.W1_j ----
    if (lane < 32) {
        const int j = lane;
        const float w0 = W1[j], w1 = W1[32 + j], w2 = W1[64 + j];
        ((float*)&sAB[j >> 1])[(j & 1)]     = b1[j] + ox * w0 + oy * w1 + oz * w2;
        ((float*)&sAB[j >> 1])[2 + (j & 1)] = dx * w0 + dy * w1 + dz * w2;
    }
    __builtin_amdgcn_wave_barrier();

    // ---- packed-fp32 fused MLP for two z values ----
    auto mlp2 = [&](float za, float zb, float& sga, float& sgb, uint2& ra, uint2& rb) {
        const f32x2 za2 = {za, za}, zb2 = {zb, zb};
        const f32x2 zero2 = {0.f, 0.f};
        f32x2 aSa = zero2, aSb = zero2;
        f32x2 a0a = zero2, a1a = zero2, a2a = zero2, a3a = zero2;
        f32x2 a0b = zero2, a1b = zero2, a2b = zero2, a3b = zero2;
#pragma unroll 4
        for (int t = 0; t < 16; ++t) {
            const float4 ab = sAB[t];
            const f32x2 A2 = {ab.x, ab.y}, B2 = {ab.z, ab.w};
            f32x2 ha = pk_fma_vv(za2, B2, A2);
            f32x2 hb = pk_fma_vv(zb2, B2, A2);
            ha = __builtin_elementwise_max(ha, zero2);
            hb = __builtin_elementwise_max(hb, zero2);
            const f32x2 wsg = *(const f32x2*)(wsf + WS_WS + 2 * t);
            const f32x2* wf = (const f32x2*)(wsf + WS_WF + 8 * t);
            const f32x2 w0 = wf[0], w1 = wf[1], w2 = wf[2], w3 = wf[3];
            aSa = pk_fma_sv(ha, wsg, aSa); aSb = pk_fma_sv(hb, wsg, aSb);
            a0a = pk_fma_sv(ha, w0, a0a); a0b = pk_fma_sv(hb, w0, a0b);
            a1a = pk_fma_sv(ha, w1, a1a); a1b = pk_fma_sv(hb, w1, a1b);
            a2a = pk_fma_sv(ha, w2, a2a); a2b = pk_fma_sv(hb, w2, a2b);
            a3a = pk_fma_sv(ha, w3, a3a); a3b = pk_fma_sv(hb, w3, a3b);
        }
        sga = softplus_f(b20 + aSa.x + aSa.y);
        sgb = softplus_f(b20 + aSb.x + aSb.y);
        ra = pack_rgb(sigmoid_f(rayc[0] + a0a.x + a0a.y), sigmoid_f(rayc[1] + a1a.x + a1a.y),
                      sigmoid_f(rayc[2] + a2a.x + a2a.y), sigmoid_f(rayc[3] + a3a.x + a3a.y));
        rb = pack_rgb(sigmoid_f(rayc[0] + a0b.x + a0b.y), sigmoid_f(rayc[1] + a1b.x + a1b.y),
                      sigmoid_f(rayc[2] + a2b.x + a2b.y), sigmoid_f(rayc[3] + a3b.x + a3b.y));
    };

    // ---- coarse pass: samples 2*lane, 2*lane+1 (uniform grid; no LDS for z) ----
    const float zc0 = fmaf((float)(2 * lane), dstep, nearv);
    const float zc1 = zc0 + dstep;
    float sgc0, sgc1; uint2 rc0, rc1;
    mlp2(zc0, zc1, sgc0, sgc1, rc0, rc1);

    // ---- coarse composite weights (for PDF): deltas are uniform ----
    const float dc1 = (lane == 63) ? sample_dist : dstep;
    const float ec0 = __builtin_amdgcn_exp2f(dstep * sgc0 * -1.442695041f);
    const float ec1 = __builtin_amdgcn_exp2f(dc1 * sgc1 * -1.442695041f);
    const float alc0 = 1.f - ec0, alc1 = 1.f - ec1;
    const float vc0 = ec0 + 1e-15f, vc1 = ec1 + 1e-15f;
    const float incl = scan_mul_f(vc0 * vc1);
    float excl = __shfl_up(incl, 1, 64);
    if (lane == 0) excl = 1.f;
    const float wc0 = alc0 * excl;
    const float wc1 = alc1 * (excl * vc0);

    // pdf bins j=0..125 use w[j+1]: lane l handles bins 2l, 2l+1
    const float wnext = __shfl_down(wc0, 1, 64);      // w(2l+2)
    float p0 = wc1 + 1e-5f, p1 = wnext + 1e-5f;
    if (lane == 63) { p0 = 0.f; p1 = 0.f; }
    const float s01 = p0 + p1;
    const float cinc = scan_add_f(s01);
    const float total = __builtin_bit_cast(float,
        __builtin_amdgcn_readlane(__builtin_bit_cast(int, cinc), 63));
    const float rtot = __builtin_amdgcn_rcpf(total);
    const float cexcl = cinc - s01;
    if (lane < 63) {
        const float cdfA = (cexcl + p0) * rtot;        // index 2l+1
        const float cdfB = (cexcl + p0 + p1) * rtot;   // index 2l+2
        sCdf[2 * lane + 1] = cdfA;
        sCdf[2 * lane + 2] = cdfB;
        // cnt_m = #{k: u_k < cdf_m}, u_k = (k+0.5)/128  (closed form)
        int cA = (int)ceilf(fmaf(128.f, cdfA, -0.5f));
        int cB = (int)ceilf(fmaf(128.f, cdfB, -0.5f));
        cA = min(max(cA, 0), 128); cB = min(max(cB, 0), 128);
        atomicAdd(&sHU[cA], 1);
        atomicAdd(&sHU[cB], 1);
    } else {
        sCdf[0] = 0.f;
        atomicAdd(&sHU[0], 1);   // m = 0, cdf_0 = 0 -> cnt = 0
    }
    __builtin_amdgcn_wave_barrier();

    // ---- inds_k = #{m: cnt_m <= k} via histogram prefix ----
    const int2 hu = *(const int2*)(sHU + 2 * lane);
    const int hs = hu.x + hu.y;
    const int hscan = scan_add_i(hs);
    const int hexcl = hscan - hs;
    const int indsA = hexcl + hu.x;     // for u at k=2l
    const int indsB = hexcl + hs;       // for u at k=2l+1

    const float mstep = fmn * (1.0f / 127.0f);
    auto lerp_z = [&](int inds, float u) -> float {
        const int below = inds - 1;
        const int above = min(inds, 126);
        const float cb = sCdf[below], ca = sCdf[above];
        const float bb = fmaf((float)below + 0.5f, mstep, nearv);   // uniform-grid midpoint
        const float ba = fmaf((float)above + 0.5f, mstep, nearv);
        float den = ca - cb;
        if (den < 1e-5f) den = 1.0f;
        const float t = (u - cb) * __builtin_amdgcn_rcpf(den);
        return bb + t * (ba - bb);
    };
    const float zf0 = lerp_z(indsA, ((float)(2 * lane) + 0.5f) * (1.0f / 128.f));
    const float zf1 = lerp_z(indsB, ((float)(2 * lane) + 1.5f) * (1.0f / 128.f));

    float sgf0, sgf1; uint2 rf0, rf1;
    mlp2(zf0, zf1, sgf0, sgf1, rf0, rf1);

    // rank of fine in coarse: r = #{i: zc_i <= zf} (closed form)
    const float inv_stepz = 127.0f / fmn;
    int r0 = (int)floorf((zf0 - nearv) * inv_stepz) + 1;
    int r1 = (int)floorf((zf1 - nearv) * inv_stepz) + 1;
    r0 = min(max(r0, 0), 128); r1 = min(max(r1, 0), 128);
    atomicAdd(&sHM[r0], 1);
    atomicAdd(&sHM[r1], 1);
    __builtin_amdgcn_wave_barrier();

    // ---- g(j) = #{k: r_k <= j} via histogram prefix; scatter sorted triples ----
    const int2 hm = *(const int2*)(sHM + 2 * lane);
    const int ms = hm.x + hm.y;
    const int mscan = scan_add_i(ms);
    const int mexcl = mscan - ms;
    const int dC0 = 2 * lane + (mexcl + hm.x);
    const int dC1 = 2 * lane + 1 + (mexcl + ms);
    const int dF0 = 2 * lane + r0;
    const int dF1 = 2 * lane + 1 + r1;

    auto il = [](int d) { return ((d & 3) << 6) + (d >> 2); };
    {
        const int a0 = il(dC0), a1 = il(dC1), a2 = il(dF0), a3 = il(dF1);
        sZ[a0] = zc0; sSig[a0] = sgc0; sRgb[a0] = rc0;
        sZ[a1] = zc1; sSig[a1] = sgc1; sRgb[a1] = rc1;
        sZ[a2] = zf0; sSig[a2] = sgf0; sRgb[a2] = rf0;
        sZ[a3] = zf1; sSig[a3] = sgf1; sRgb[a3] = rf1;
    }
    __builtin_amdgcn_wave_barrier();

    // ---- final compositing: 4 sorted samples per lane (il4 reads, conflict-free) ----
    const float z0 = sZ[lane],        z1 = sZ[64 + lane];
    const float z2 = sZ[128 + lane],  z3 = sZ[192 + lane];
    const float g0 = sSig[lane],       g1 = sSig[64 + lane];
    const float g2 = sSig[128 + lane], g3 = sSig[192 + lane];
    const uint2 q0 = sRgb[lane],       q1 = sRgb[64 + lane];
    const uint2 q2 = sRgb[128 + lane], q3 = sRgb[192 + lane];

    const float znx = __shfl_down(z0, 1, 64);
    const float dd0 = z1 - z0;
    const float dd1 = z2 - z1;
    const float dd2 = z3 - z2;
    const float dd3 = (lane == 63) ? sample_dist : (znx - z3);

    const float e0 = __builtin_amdgcn_exp2f(dd0 * g0 * -1.442695041f);
    const float e1 = __builtin_amdgcn_exp2f(dd1 * g1 * -1.442695041f);
    const float e2 = __builtin_amdgcn_exp2f(dd2 * g2 * -1.442695041f);
    const float e3 = __builtin_amdgcn_exp2f(dd3 * g3 * -1.442695041f);
    const float al0 = 1.f - e0, al1 = 1.f - e1, al2 = 1.f - e2, al3 = 1.f - e3;
    const float v0 = e0 + 1e-15f, v1 = e1 + 1e-15f, v2 = e2 + 1e-15f, v3 = e3 + 1e-15f;

    const float incl2 = scan_mul_f(v0 * v1 * v2 * v3);
    float T0 = __shfl_up(incl2, 1, 64);
    if (lane == 0) T0 = 1.f;
    const float T1 = T0 * v0, T2 = T1 * v1, T3 = T2 * v2;
    const float w0 = al0 * T0, w1 = al1 * T1, w2 = al2 * T2, w3 = al3 * T3;

    const float inv_fn = 1.0f / fmn;
    const float oz0 = clampf((z0 - nearv) * inv_fn, 0.f, 1.f);
    const float oz1 = clampf((z1 - nearv) * inv_fn, 0.f, 1.f);
    const float oz2 = clampf((z2 - nearv) * inv_fn, 0.f, 1.f);
    const float oz3 = clampf((z3 - nearv) * inv_fn, 0.f, 1.f);

    float r0c[4], r1c[4], r2c[4], r3c[4];
    unpack_rgb(q0.x, q0.y, r0c);
    unpack_rgb(q1.x, q1.y, r1c);
    unpack_rgb(q2.x, q2.y, r2c);
    unpack_rgb(q3.x, q3.y, r3c);

    float vals[6];
#pragma unroll
    for (int c = 0; c < 4; ++c)
        vals[c] = w0 * r0c[c] + w1 * r1c[c] + w2 * r2c[c] + w3 * r3c[c];
    vals[4] = w0 * oz0 + w1 * oz1 + w2 * oz2 + w3 * oz3;
    vals[5] = w0 + w1 + w2 + w3;

    // 6 reductions via DPP add-scan; lane 63 holds the totals
#pragma unroll
    for (int q = 0; q < 6; ++q) vals[q] = scan_add_f(vals[q]);

    if (lane == 63) {
        const float wsum = vals[5];
#pragma unroll
        for (int c = 0; c < 4; ++c)
            out[ray * 4 + c] = vals[c] + (1.0f - wsum);
        out[4 * N_RAYS + ray] = vals[4];
        out[5 * N_RAYS + ray] = wsum;
    }
}

extern "C" void kernel_launch(void* const* d_in, const int* in_sizes, int n_in,
                              void* d_out, int out_size, void* d_ws, size_t ws_size,
                              hipStream_t stream) {
    const float* rays_o = (const float*)d_in[0];
    const float* rays_d = (const float*)d_in[1];
    const float* W1 = (const float*)d_in[2];
    const float* b1 = (const float*)d_in[3];
    const float* W2 = (const float*)d_in[4];
    const float* b2 = (const float*)d_in[5];
    const float* Wc = (const float*)d_in[6];
    const float* Wd = (const float*)d_in[7];
    const float* bc = (const float*)d_in[8];
    float* out = (float*)d_out;
    float* ws  = (float*)d_ws;

    hipLaunchKernelGGL(nerf_prep_kernel, dim3(1), dim3(128), 0, stream,
                       W2, b2, Wc, bc, ws);
    hipLaunchKernelGGL(nerf_render_kernel, dim3(N_RAYS / RPB), dim3(256), 0, stream,
                       rays_o, rays_d, W1, b1, Wd, ws, out);
}

// Round 9
// 33.881 us; speedup vs baseline: 10.2220x; 1.3739x over previous
//
#include <hip/hip_runtime.h>
#include <math.h>

#define N_RAYS 16384
#define S 128
#define FEAT 15
#define BOUNDF 2.0f
#define MIN_NEAR 0.05f
#define RPB 4              // rays (waves) per 256-thread block
#define PRW 1552           // per-ray LDS words (6208 B)

// per-ray LDS word offsets.  Aliasing is strictly sequenced:
//  stage [5][132] (0..659) and AB/BIAS are fully consumed before the
//  sorted arrays (0..1023) are written at the end.
#define O_STG  0           // 5 x 132 f32 staging of MFMA outputs
#define O_ZS   0           // sorted z   il4 [256]
#define O_SIG  256         // sorted sig il4 [256]
#define O_RGB  512         // sorted rgb il4 [256 x uint2]
#define O_AB   704         // 16 x float4 {A even,A odd,B even,B odd}
#define O_BIAS 768         // 16 f32 acc-init bias per output col
#define O_CDF  1024        // 128 f32
#define O_ZF   1152        // 128 f32 fine z
#define O_HU   1280        // 129 int (pad 132)
#define O_HM   1412        // 129 int (pad 132)

typedef __fp16 h16x2 __attribute__((ext_vector_type(2)));
typedef _Float16 f16x8 __attribute__((ext_vector_type(8)));
typedef float f32x4 __attribute__((ext_vector_type(4)));

// ws float layout: [0..255] B-fragment (64 lanes x 4 dwords of f16 pairs)
//                  [256..259] bfused[c]   [260] b2_0
#define WS_FRAG 0
#define WS_BF   256
#define WS_B20  260

__device__ __forceinline__ h16x2 pk_fma_f16(h16x2 a, h16x2 b, h16x2 c) {
    h16x2 d;
    asm("v_pk_fma_f16 %0, %1, %2, %3" : "=v"(d) : "v"(a), "v"(b), "v"(c));
    return d;
}
__device__ __forceinline__ h16x2 pk_relu_f16(h16x2 a) {
    h16x2 d;
    asm("v_pk_max_f16 %0, %1, 0" : "=v"(d) : "v"(a));
    return d;
}

__device__ __forceinline__ float softplus_f(float x) {
    float e = __builtin_amdgcn_exp2f(x * 1.442695041f);
    return 0.69314718056f * __builtin_amdgcn_logf(1.0f + e);
}
__device__ __forceinline__ float sigmoid_f(float x) {
    float e = __builtin_amdgcn_exp2f(x * -1.442695041f);
    return __builtin_amdgcn_rcpf(1.0f + e);
}
__device__ __forceinline__ float clampf(float x, float lo, float hi) {
    return fminf(fmaxf(x, lo), hi);
}
__device__ __forceinline__ uint2 pack_rgb(float c0, float c1, float c2, float c3) {
    h16x2 p0 = __builtin_amdgcn_cvt_pkrtz(c0, c1);
    h16x2 p1 = __builtin_amdgcn_cvt_pkrtz(c2, c3);
    uint2 r;
    r.x = __builtin_bit_cast(unsigned int, p0);
    r.y = __builtin_bit_cast(unsigned int, p1);
    return r;
}
__device__ __forceinline__ void unpack_rgb(unsigned int lo, unsigned int hi, float* c) {
    h16x2 p0 = __builtin_bit_cast(h16x2, lo);
    h16x2 p1 = __builtin_bit_cast(h16x2, hi);
    c[0] = (float)p0.x; c[1] = (float)p0.y; c[2] = (float)p1.x; c[3] = (float)p1.y;
}

// ---- DPP wave64 inclusive scans ----
template<int CTRL, int RMASK>
__device__ __forceinline__ float dppf(float old, float v) {
    int r = __builtin_amdgcn_update_dpp(__builtin_bit_cast(int, old),
                                        __builtin_bit_cast(int, v),
                                        CTRL, RMASK, 0xf, false);
    return __builtin_bit_cast(float, r);
}
template<int CTRL, int RMASK>
__device__ __forceinline__ int dppi(int old, int v) {
    return __builtin_amdgcn_update_dpp(old, v, CTRL, RMASK, 0xf, false);
}
__device__ __forceinline__ float scan_mul_f(float v) {
    v *= dppf<0x111, 0xf>(1.0f, v);
    v *= dppf<0x112, 0xf>(1.0f, v);
    v *= dppf<0x114, 0xf>(1.0f, v);
    v *= dppf<0x118, 0xf>(1.0f, v);
    v *= dppf<0x142, 0xa>(1.0f, v);
    v *= dppf<0x143, 0xc>(1.0f, v);
    return v;
}
__device__ __forceinline__ float scan_add_f(float v) {
    v += dppf<0x111, 0xf>(0.0f, v);
    v += dppf<0x112, 0xf>(0.0f, v);
    v += dppf<0x114, 0xf>(0.0f, v);
    v += dppf<0x118, 0xf>(0.0f, v);
    v += dppf<0x142, 0xa>(0.0f, v);
    v += dppf<0x143, 0xc>(0.0f, v);
    return v;
}
__device__ __forceinline__ int scan_add_i(int v) {
    v += dppi<0x111, 0xf>(0, v);
    v += dppi<0x112, 0xf>(0, v);
    v += dppi<0x114, 0xf>(0, v);
    v += dppi<0x118, 0xf>(0, v);
    v += dppi<0x142, 0xa>(0, v);
    v += dppi<0x143, 0xc>(0, v);
    return v;
}

// B-fragment prep: W2full[k][n] (n=0 sigma col, 1..4 fused rgb cols, else 0)
// packed f16 in MFMA B layout: lane t holds B[(t>>4)*8+j][t&15], j=0..7.
extern "C" __global__ __launch_bounds__(64)
void nerf_prep_kernel(const float* __restrict__ W2, const float* __restrict__ b2,
                      const float* __restrict__ Wc, const float* __restrict__ bc,
                      float* __restrict__ ws) {
    const int t = threadIdx.x;          // 64 threads
    const int col = t & 15, kb = t >> 4;
    float v[8];
#pragma unroll
    for (int j = 0; j < 8; ++j) {
        const int k = kb * 8 + j;
        float x = 0.0f;
        if (col == 0) {
            x = W2[k * 16];
        } else if (col <= 4) {
#pragma unroll
            for (int f = 0; f < FEAT; ++f) x += W2[k * 16 + 1 + f] * Wc[f * 4 + (col - 1)];
        }
        v[j] = x;
    }
#pragma unroll
    for (int m = 0; m < 4; ++m) {
        h16x2 p = __builtin_amdgcn_cvt_pkrtz(v[2 * m], v[2 * m + 1]);
        ws[WS_FRAG + t * 4 + m] = __builtin_bit_cast(float, p);
    }
    if (t < 4) {
        float b = bc[t];
#pragma unroll
        for (int f = 0; f < FEAT; ++f) b += b2[1 + f] * Wc[f * 4 + t];
        ws[WS_BF + t] = b;
    }
    if (t == 0) ws[WS_B20] = b2[0];
}

struct CoarseTag { static constexpr bool fine = false; };
struct FineTag   { static constexpr bool fine = true;  };

extern "C" __global__ __launch_bounds__(256)
void nerf_render_kernel(const float* __restrict__ rays_o,
                        const float* __restrict__ rays_d,
                        const float* __restrict__ W1, const float* __restrict__ b1,
                        const float* __restrict__ Wd,
                        const float* __restrict__ wsf,
                        float* __restrict__ out) {
    const int wv   = threadIdx.x >> 6;
    const int lane = threadIdx.x & 63;
    const int ray  = blockIdx.x * RPB + wv;
    const int col16 = lane & 15;        // sample-in-tile (A row / C col role)
    const int kb    = lane >> 4;        // k-block / C row-group

    __shared__ __align__(16) float smem[RPB][PRW];
    float*  base  = &smem[wv][0];
    float*  sStg  = base + O_STG;
    float*  sZs   = base + O_ZS;
    float*  sSig  = base + O_SIG;
    uint2*  sRgb  = (uint2*)(base + O_RGB);
    float4* sAB   = (float4*)(base + O_AB);
    float*  sBias = base + O_BIAS;
    float*  sCdf  = base + O_CDF;
    float*  sZf   = base + O_ZF;
    int*    sHU   = (int*)(base + O_HU);
    int*    sHM   = (int*)(base + O_HM);

    // ---- ray setup (uniform per wave) ----
    const float ox = rays_o[ray * 3 + 0], oy = rays_o[ray * 3 + 1], oz = rays_o[ray * 3 + 2];
    const float dx = rays_d[ray * 3 + 0], dy = rays_d[ray * 3 + 1], dz = rays_d[ray * 3 + 2];

    auto invd = [](float d) { float dd = (fabsf(d) < 1e-9f) ? 1e-9f : d; return 1.0f / dd; };
    const float ixv = invd(dx), iyv = invd(dy), izv = invd(dz);
    const float t1x = (-BOUNDF - ox) * ixv, t2x = (BOUNDF - ox) * ixv;
    const float t1y = (-BOUNDF - oy) * iyv, t2y = (BOUNDF - oy) * iyv;
    const float t1z = (-BOUNDF - oz) * izv, t2z = (BOUNDF - oz) * izv;
    float nearv = fmaxf(fmaxf(fminf(t1x, t2x), fminf(t1y, t2y)), fminf(t1z, t2z));
    nearv = fmaxf(nearv, MIN_NEAR);
    float farv = fminf(fminf(fmaxf(t1x, t2x), fmaxf(t1y, t2y)), fmaxf(t1z, t2z));
    farv = fmaxf(farv, nearv + 1e-5f);
    const float fmn = farv - nearv;
    const float sample_dist = fmn * (1.0f / (float)S);
    const float dstep = fmn * (1.0f / 127.0f);

    // zero histograms (own regions, never clobbered)
    sHU[lane] = 0; sHU[64 + lane] = 0;
    sHM[lane] = 0; sHM[64 + lane] = 0;
    if (lane == 0) { sHU[128] = 0; sHM[128] = 0; }

    // layer-1 fold: A_j = b1_j + o.W1_j ; B_j = d.W1_j (interleaved pairs)
    if (lane < 32) {
        const int j = lane;
        const float w0 = W1[j], w1 = W1[32 + j], w2 = W1[64 + j];
        ((float*)&sAB[j >> 1])[(j & 1)]     = b1[j] + ox * w0 + oy * w1 + oz * w2;
        ((float*)&sAB[j >> 1])[2 + (j & 1)] = dx * w0 + dy * w1 + dz * w2;
    }
    // acc-init bias per output col: col0 = b2_0; col1..4 = bfused + d@Wd; else 0
    if (lane < 16) {
        float b = 0.0f;
        if (lane == 0) b = wsf[WS_B20];
        else if (lane <= 4) {
            const int c = lane - 1;
            b = wsf[WS_BF + c] + dx * Wd[c] + dy * Wd[4 + c] + dz * Wd[8 + c];
        }
        sBias[lane] = b;
    }
    __builtin_amdgcn_wave_barrier();

    // ---- per-lane fragments ----
    h16x2 Af[4], Bf[4];
#pragma unroll
    for (int m = 0; m < 4; ++m) {
        const float4 ab = sAB[kb * 4 + m];
        Af[m] = __builtin_amdgcn_cvt_pkrtz(ab.x, ab.y);
        Bf[m] = __builtin_amdgcn_cvt_pkrtz(ab.z, ab.w);
    }
    const float4 frw = ((const float4*)wsf)[lane];      // B-frag (16B/lane)
    const f16x8 bfrag = __builtin_bit_cast(f16x8, frw);
    const float bv = sBias[col16];
    f32x4 accB; accB[0] = bv; accB[1] = bv; accB[2] = bv; accB[3] = bv;

    // ---- MFMA MLP pass: 8 tiles of 16 samples, K=32, f16 in / f32 out ----
    auto mfma_pass = [&](auto tag) {
#pragma unroll
        for (int t = 0; t < 8; ++t) {
            float zs;
            if constexpr (decltype(tag)::fine) zs = sZf[t * 16 + col16];
            else                               zs = fmaf((float)(t * 16 + col16), dstep, nearv);
            const h16x2 z2 = __builtin_amdgcn_cvt_pkrtz(zs, zs);
            h16x2 h0 = pk_relu_f16(pk_fma_f16(Bf[0], z2, Af[0]));
            h16x2 h1 = pk_relu_f16(pk_fma_f16(Bf[1], z2, Af[1]));
            h16x2 h2 = pk_relu_f16(pk_fma_f16(Bf[2], z2, Af[2]));
            h16x2 h3 = pk_relu_f16(pk_fma_f16(Bf[3], z2, Af[3]));
            uint4 au;
            au.x = __builtin_bit_cast(unsigned int, h0);
            au.y = __builtin_bit_cast(unsigned int, h1);
            au.z = __builtin_bit_cast(unsigned int, h2);
            au.w = __builtin_bit_cast(unsigned int, h3);
            const f16x8 afrag = __builtin_bit_cast(f16x8, au);
            f32x4 acc = __builtin_amdgcn_mfma_f32_16x16x32_f16(afrag, bfrag, accB, 0, 0, 0);
            if (col16 < 5) {
#pragma unroll
                for (int i = 0; i < 4; ++i)
                    sStg[col16 * 132 + t * 16 + kb * 4 + i] = acc[i];
            }
        }
    };
    auto readback = [&](int p, float& sg, uint2& rgb) {
        const float c0 = sStg[0 * 132 + p];
        const float c1 = sStg[1 * 132 + p];
        const float c2 = sStg[2 * 132 + p];
        const float c3 = sStg[3 * 132 + p];
        const float c4 = sStg[4 * 132 + p];
        sg  = softplus_f(c0);
        rgb = pack_rgb(sigmoid_f(c1), sigmoid_f(c2), sigmoid_f(c3), sigmoid_f(c4));
    };

    // ---- coarse pass ----
    mfma_pass(CoarseTag{});
    __builtin_amdgcn_wave_barrier();
    float sgc0, sgc1; uint2 rc0, rc1;
    readback(2 * lane,     sgc0, rc0);
    readback(2 * lane + 1, sgc1, rc1);
    const float zc0 = fmaf((float)(2 * lane), dstep, nearv);
    const float zc1 = zc0 + dstep;

    // ---- coarse composite weights (for PDF) ----
    const float dc1 = (lane == 63) ? sample_dist : dstep;
    const float ec0 = __builtin_amdgcn_exp2f(dstep * sgc0 * -1.442695041f);
    const float ec1 = __builtin_amdgcn_exp2f(dc1 * sgc1 * -1.442695041f);
    const float alc0 = 1.f - ec0, alc1 = 1.f - ec1;
    const float vc0 = ec0 + 1e-15f, vc1 = ec1 + 1e-15f;
    const float incl = scan_mul_f(vc0 * vc1);
    float excl = __shfl_up(incl, 1, 64);
    if (lane == 0) excl = 1.f;
    const float wc0 = alc0 * excl;
    const float wc1 = alc1 * (excl * vc0);

    const float wnext = __shfl_down(wc0, 1, 64);      // w(2l+2)
    float p0 = wc1 + 1e-5f, p1 = wnext + 1e-5f;
    if (lane == 63) { p0 = 0.f; p1 = 0.f; }
    const float s01 = p0 + p1;
    const float cinc = scan_add_f(s01);
    const float total = __builtin_bit_cast(float,
        __builtin_amdgcn_readlane(__builtin_bit_cast(int, cinc), 63));
    const float rtot = __builtin_amdgcn_rcpf(total);
    const float cexcl = cinc - s01;
    if (lane < 63) {
        const float cdfA = (cexcl + p0) * rtot;
        const float cdfB = (cexcl + p0 + p1) * rtot;
        sCdf[2 * lane + 1] = cdfA;
        sCdf[2 * lane + 2] = cdfB;
        int cA = (int)ceilf(fmaf(128.f, cdfA, -0.5f));
        int cB = (int)ceilf(fmaf(128.f, cdfB, -0.5f));
        cA = min(max(cA, 0), 128); cB = min(max(cB, 0), 128);
        atomicAdd(&sHU[cA], 1);
        atomicAdd(&sHU[cB], 1);
    } else {
        sCdf[0] = 0.f;
        atomicAdd(&sHU[0], 1);
    }
    __builtin_amdgcn_wave_barrier();

    // ---- inds via histogram prefix; closed-form bin midpoints ----
    const int2 hu = *(const int2*)(sHU + 2 * lane);
    const int hs = hu.x + hu.y;
    const int hscan = scan_add_i(hs);
    const int hexcl = hscan - hs;
    const int indsA = hexcl + hu.x;
    const int indsB = hexcl + hs;

    auto lerp_z = [&](int inds, float u) -> float {
        const int below = inds - 1;
        const int above = min(inds, 126);
        const float cb = sCdf[below], ca = sCdf[above];
        const float bb = fmaf((float)below + 0.5f, dstep, nearv);
        const float ba = fmaf((float)above + 0.5f, dstep, nearv);
        float den = ca - cb;
        if (den < 1e-5f) den = 1.0f;
        const float t = (u - cb) * __builtin_amdgcn_rcpf(den);
        return bb + t * (ba - bb);
    };
    const float zf0 = lerp_z(indsA, ((float)(2 * lane) + 0.5f) * (1.0f / 128.f));
    const float zf1 = lerp_z(indsB, ((float)(2 * lane) + 1.5f) * (1.0f / 128.f));
    sZf[2 * lane]     = zf0;
    sZf[2 * lane + 1] = zf1;

    // rank of fine in coarse (closed form) + histogram
    const float inv_stepz = 127.0f / fmn;
    int r0 = (int)floorf((zf0 - nearv) * inv_stepz) + 1;
    int r1 = (int)floorf((zf1 - nearv) * inv_stepz) + 1;
    r0 = min(max(r0, 0), 128); r1 = min(max(r1, 0), 128);
    atomicAdd(&sHM[r0], 1);
    atomicAdd(&sHM[r1], 1);
    __builtin_amdgcn_wave_barrier();

    // ---- fine pass ----
    mfma_pass(FineTag{});
    __builtin_amdgcn_wave_barrier();
    float sgf0, sgf1; uint2 rf0, rf1;
    readback(2 * lane,     sgf0, rf0);
    readback(2 * lane + 1, sgf1, rf1);
    __builtin_amdgcn_wave_barrier();    // stage fully consumed before sorted writes

    // ---- merge ranks via histogram prefix; scatter sorted triples ----
    const int2 hm = *(const int2*)(sHM + 2 * lane);
    const int ms = hm.x + hm.y;
    const int mscan = scan_add_i(ms);
    const int mexcl = mscan - ms;
    const int dC0 = 2 * lane + (mexcl + hm.x);
    const int dC1 = 2 * lane + 1 + (mexcl + ms);
    const int dF0 = 2 * lane + r0;
    const int dF1 = 2 * lane + 1 + r1;

    auto il = [](int d) { return ((d & 3) << 6) + (d >> 2); };
    {
        const int a0 = il(dC0), a1 = il(dC1), a2 = il(dF0), a3 = il(dF1);
        sZs[a0] = zc0; sSig[a0] = sgc0; sRgb[a0] = rc0;
        sZs[a1] = zc1; sSig[a1] = sgc1; sRgb[a1] = rc1;
        sZs[a2] = zf0; sSig[a2] = sgf0; sRgb[a2] = rf0;
        sZs[a3] = zf1; sSig[a3] = sgf1; sRgb[a3] = rf1;
    }
    __builtin_amdgcn_wave_barrier();

    // ---- final compositing: 4 sorted samples per lane (il4 reads) ----
    const float z0 = sZs[lane],        z1 = sZs[64 + lane];
    const float z2 = sZs[128 + lane],  z3 = sZs[192 + lane];
    const float g0 = sSig[lane],       g1 = sSig[64 + lane];
    const float g2 = sSig[128 + lane], g3 = sSig[192 + lane];
    const uint2 q0 = sRgb[lane],       q1 = sRgb[64 + lane];
    const uint2 q2 = sRgb[128 + lane], q3 = sRgb[192 + lane];

    const float znx = __shfl_down(z0, 1, 64);
    const float dd0 = z1 - z0;
    const float dd1 = z2 - z1;
    const float dd2 = z3 - z2;
    const float dd3 = (lane == 63) ? sample_dist : (znx - z3);

    const float e0 = __builtin_amdgcn_exp2f(dd0 * g0 * -1.442695041f);
    const float e1 = __builtin_amdgcn_exp2f(dd1 * g1 * -1.442695041f);
    const float e2 = __builtin_amdgcn_exp2f(dd2 * g2 * -1.442695041f);
    const float e3 = __builtin_amdgcn_exp2f(dd3 * g3 * -1.442695041f);
    const float al0 = 1.f - e0, al1 = 1.f - e1, al2 = 1.f - e2, al3 = 1.f - e3;
    const float v0 = e0 + 1e-15f, v1 = e1 + 1e-15f, v2 = e2 + 1e-15f, v3 = e3 + 1e-15f;

    const float incl2 = scan_mul_f(v0 * v1 * v2 * v3);
    float T0 = __shfl_up(incl2, 1, 64);
    if (lane == 0) T0 = 1.f;
    const float T1 = T0 * v0, T2 = T1 * v1, T3 = T2 * v2;
    const float w0 = al0 * T0, w1 = al1 * T1, w2 = al2 * T2, w3 = al3 * T3;

    const float inv_fn = 1.0f / fmn;
    const float oz0 = clampf((z0 - nearv) * inv_fn, 0.f, 1.f);
    const float oz1 = clampf((z1 - nearv) * inv_fn, 0.f, 1.f);
    const float oz2 = clampf((z2 - nearv) * inv_fn, 0.f, 1.f);
    const float oz3 = clampf((z3 - nearv) * inv_fn, 0.f, 1.f);

    float r0c[4], r1c[4], r2c[4], r3c[4];
    unpack_rgb(q0.x, q0.y, r0c);
    unpack_rgb(q1.x, q1.y, r1c);
    unpack_rgb(q2.x, q2.y, r2c);
    unpack_rgb(q3.x, q3.y, r3c);

    float vals[6];
#pragma unroll
    for (int c = 0; c < 4; ++c)
        vals[c] = w0 * r0c[c] + w1 * r1c[c] + w2 * r2c[c] + w3 * r3c[c];
    vals[4] = w0 * oz0 + w1 * oz1 + w2 * oz2 + w3 * oz3;
    vals[5] = w0 + w1 + w2 + w3;

#pragma unroll
    for (int q = 0; q < 6; ++q) vals[q] = scan_add_f(vals[q]);

    if (lane == 63) {
        const float wsum = vals[5];
#pragma unroll
        for (int c = 0; c < 4; ++c)
            out[ray * 4 + c] = vals[c] + (1.0f - wsum);
        out[4 * N_RAYS + ray] = vals[4];
        out[5 * N_RAYS + ray] = wsum;
    }
}

extern "C" void kernel_launch(void* const* d_in, const int* in_sizes, int n_in,
                              void* d_out, int out_size, void* d_ws, size_t ws_size,
                              hipStream_t stream) {
    const float* rays_o = (const float*)d_in[0];
    const float* rays_d = (const float*)d_in[1];
    const float* W1 = (const float*)d_in[2];
    const float* b1 = (const float*)d_in[3];
    const float* W2 = (const float*)d_in[4];
    const float* b2 = (const float*)d_in[5];
    const float* Wc = (const float*)d_in[6];
    const float* Wd = (const float*)d_in[7];
    const float* bc = (const float*)d_in[8];
    float* out = (float*)d_out;
    float* ws  = (float*)d_ws;

    hipLaunchKernelGGL(nerf_prep_kernel, dim3(1), dim3(64), 0, stream,
                       W2, b2, Wc, bc, ws);
    hipLaunchKernelGGL(nerf_render_kernel, dim3(N_RAYS / RPB), dim3(256), 0, stream,
                       rays_o, rays_d, W1, b1, Wd, ws, out);
}

// Round 10
// 33.636 us; speedup vs baseline: 10.2967x; 1.0073x over previous
//
#include <hip/hip_runtime.h>
#include <math.h>

#define N_RAYS 16384
#define S 128
#define FEAT 15
#define BOUNDF 2.0f
#define MIN_NEAR 0.05f
#define RPB 4              // rays (waves) per 256-thread block
#define PRW 1152           // per-ray LDS words (4608 B)

// per-ray LDS word offsets.  Aliasing is strictly sequenced (single wave,
// in-order DS ops):
//   stage [5][132] (0..659)  : live during each MLP pass + its readback
//   cdf (0..127)             : written after coarse readback (stage dead),
//                              consumed in lerp_z before fine pass rewrites stage
//   HU 660..788, HM 792..920 : zeroed at start, consumed before the sorted
//                              scatter writes 0..1023 (reads precede writes)
//   sorted zs/sig/rgb 0..1023: written last
//   zf 1024..1151            : no aliasing (read during fine pass)
#define O_STG  0
#define O_CDF  0
#define O_ZS   0
#define O_SIG  256
#define O_RGB  512
#define O_HU   660
#define O_HM   792
#define O_ZF   1024
#define O_AB   (PRW - 80)   // 16 x float4 {A even,A odd,B even,B odd} = 1072..1135
#define O_BIAS (PRW - 16)   // 16 f32 acc-init bias per output col = 1136..1151

// NOTE: O_AB/O_BIAS overlap O_ZF? 1072..1151 vs zf 1024..1151 -> conflict!
// zf only uses 1024..1151 (128 words) and AB/BIAS need 80 words; PRW bumped:
#undef O_AB
#undef O_BIAS
#undef PRW
#define PRW 1232            // 1152 + 80
#define O_AB   1152         // 16 x float4
#define O_BIAS 1216         // 16 f32

typedef __fp16 h16x2 __attribute__((ext_vector_type(2)));
typedef _Float16 f16x8 __attribute__((ext_vector_type(8)));
typedef float f32x4 __attribute__((ext_vector_type(4)));

// ws float layout: [0..255] B-fragment (64 lanes x 4 dwords of f16 pairs)
//                  [256..259] bfused[c]   [260] b2_0
#define WS_FRAG 0
#define WS_BF   256
#define WS_B20  260

__device__ __forceinline__ h16x2 pk_fma_f16(h16x2 a, h16x2 b, h16x2 c) {
    h16x2 d;
    asm("v_pk_fma_f16 %0, %1, %2, %3" : "=v"(d) : "v"(a), "v"(b), "v"(c));
    return d;
}
__device__ __forceinline__ h16x2 pk_relu_f16(h16x2 a) {
    h16x2 d;
    asm("v_pk_max_f16 %0, %1, 0" : "=v"(d) : "v"(a));
    return d;
}

__device__ __forceinline__ float softplus_f(float x) {
    float e = __builtin_amdgcn_exp2f(x * 1.442695041f);
    return 0.69314718056f * __builtin_amdgcn_logf(1.0f + e);
}
__device__ __forceinline__ float sigmoid_f(float x) {
    float e = __builtin_amdgcn_exp2f(x * -1.442695041f);
    return __builtin_amdgcn_rcpf(1.0f + e);
}
__device__ __forceinline__ float clampf(float x, float lo, float hi) {
    return fminf(fmaxf(x, lo), hi);
}
__device__ __forceinline__ uint2 pack_rgb(float c0, float c1, float c2, float c3) {
    h16x2 p0 = __builtin_amdgcn_cvt_pkrtz(c0, c1);
    h16x2 p1 = __builtin_amdgcn_cvt_pkrtz(c2, c3);
    uint2 r;
    r.x = __builtin_bit_cast(unsigned int, p0);
    r.y = __builtin_bit_cast(unsigned int, p1);
    return r;
}
__device__ __forceinline__ void unpack_rgb(unsigned int lo, unsigned int hi, float* c) {
    h16x2 p0 = __builtin_bit_cast(h16x2, lo);
    h16x2 p1 = __builtin_bit_cast(h16x2, hi);
    c[0] = (float)p0.x; c[1] = (float)p0.y; c[2] = (float)p1.x; c[3] = (float)p1.y;
}

// ---- DPP wave64 inclusive scans ----
template<int CTRL, int RMASK>
__device__ __forceinline__ float dppf(float old, float v) {
    int r = __builtin_amdgcn_update_dpp(__builtin_bit_cast(int, old),
                                        __builtin_bit_cast(int, v),
                                        CTRL, RMASK, 0xf, false);
    return __builtin_bit_cast(float, r);
}
template<int CTRL, int RMASK>
__device__ __forceinline__ int dppi(int old, int v) {
    return __builtin_amdgcn_update_dpp(old, v, CTRL, RMASK, 0xf, false);
}
__device__ __forceinline__ float scan_mul_f(float v) {
    v *= dppf<0x111, 0xf>(1.0f, v);
    v *= dppf<0x112, 0xf>(1.0f, v);
    v *= dppf<0x114, 0xf>(1.0f, v);
    v *= dppf<0x118, 0xf>(1.0f, v);
    v *= dppf<0x142, 0xa>(1.0f, v);
    v *= dppf<0x143, 0xc>(1.0f, v);
    return v;
}
__device__ __forceinline__ float scan_add_f(float v) {
    v += dppf<0x111, 0xf>(0.0f, v);
    v += dppf<0x112, 0xf>(0.0f, v);
    v += dppf<0x114, 0xf>(0.0f, v);
    v += dppf<0x118, 0xf>(0.0f, v);
    v += dppf<0x142, 0xa>(0.0f, v);
    v += dppf<0x143, 0xc>(0.0f, v);
    return v;
}
__device__ __forceinline__ int scan_add_i(int v) {
    v += dppi<0x111, 0xf>(0, v);
    v += dppi<0x112, 0xf>(0, v);
    v += dppi<0x114, 0xf>(0, v);
    v += dppi<0x118, 0xf>(0, v);
    v += dppi<0x142, 0xa>(0, v);
    v += dppi<0x143, 0xc>(0, v);
    return v;
}

// B-fragment prep: W2full[k][n] (n=0 sigma col, 1..4 fused rgb cols, else 0)
// packed f16 in MFMA B layout: lane t holds B[(t>>4)*8+j][t&15], j=0..7.
extern "C" __global__ __launch_bounds__(64)
void nerf_prep_kernel(const float* __restrict__ W2, const float* __restrict__ b2,
                      const float* __restrict__ Wc, const float* __restrict__ bc,
                      float* __restrict__ ws) {
    const int t = threadIdx.x;          // 64 threads
    const int col = t & 15, kb = t >> 4;
    float v[8];
#pragma unroll
    for (int j = 0; j < 8; ++j) {
        const int k = kb * 8 + j;
        float x = 0.0f;
        if (col == 0) {
            x = W2[k * 16];
        } else if (col <= 4) {
#pragma unroll
            for (int f = 0; f < FEAT; ++f) x += W2[k * 16 + 1 + f] * Wc[f * 4 + (col - 1)];
        }
        v[j] = x;
    }
#pragma unroll
    for (int m = 0; m < 4; ++m) {
        h16x2 p = __builtin_amdgcn_cvt_pkrtz(v[2 * m], v[2 * m + 1]);
        ws[WS_FRAG + t * 4 + m] = __builtin_bit_cast(float, p);
    }
    if (t < 4) {
        float b = bc[t];
#pragma unroll
        for (int f = 0; f < FEAT; ++f) b += b2[1 + f] * Wc[f * 4 + t];
        ws[WS_BF + t] = b;
    }
    if (t == 0) ws[WS_B20] = b2[0];
}

struct CoarseTag { static constexpr bool fine = false; };
struct FineTag   { static constexpr bool fine = true;  };

extern "C" __global__ __launch_bounds__(256, 6)
void nerf_render_kernel(const float* __restrict__ rays_o,
                        const float* __restrict__ rays_d,
                        const float* __restrict__ W1, const float* __restrict__ b1,
                        const float* __restrict__ Wd,
                        const float* __restrict__ wsf,
                        float* __restrict__ out) {
    const int wv   = threadIdx.x >> 6;
    const int lane = threadIdx.x & 63;
    const int ray  = blockIdx.x * RPB + wv;
    const int col16 = lane & 15;        // output col (C layout)
    const int kb    = lane >> 4;        // C row-group

    __shared__ __align__(16) float smem[RPB][PRW];
    float*  base  = &smem[wv][0];
    float*  sStg  = base + O_STG;
    float*  sZs   = base + O_ZS;
    float*  sSig  = base + O_SIG;
    uint2*  sRgb  = (uint2*)(base + O_RGB);
    float4* sAB   = (float4*)(base + O_AB);
    float*  sBias = base + O_BIAS;
    float*  sCdf  = base + O_CDF;
    float*  sZf   = base + O_ZF;
    int*    sHU   = (int*)(base + O_HU);
    int*    sHM   = (int*)(base + O_HM);

    // ---- ray setup (uniform per wave) ----
    const float ox = rays_o[ray * 3 + 0], oy = rays_o[ray * 3 + 1], oz = rays_o[ray * 3 + 2];
    const float dx = rays_d[ray * 3 + 0], dy = rays_d[ray * 3 + 1], dz = rays_d[ray * 3 + 2];

    auto invd = [](float d) { float dd = (fabsf(d) < 1e-9f) ? 1e-9f : d; return 1.0f / dd; };
    const float ixv = invd(dx), iyv = invd(dy), izv = invd(dz);
    const float t1x = (-BOUNDF - ox) * ixv, t2x = (BOUNDF - ox) * ixv;
    const float t1y = (-BOUNDF - oy) * iyv, t2y = (BOUNDF - oy) * iyv;
    const float t1z = (-BOUNDF - oz) * izv, t2z = (BOUNDF - oz) * izv;
    float nearv = fmaxf(fmaxf(fminf(t1x, t2x), fminf(t1y, t2y)), fminf(t1z, t2z));
    nearv = fmaxf(nearv, MIN_NEAR);
    float farv = fminf(fminf(fmaxf(t1x, t2x), fmaxf(t1y, t2y)), fmaxf(t1z, t2z));
    farv = fmaxf(farv, nearv + 1e-5f);
    const float fmn = farv - nearv;
    const float sample_dist = fmn * (1.0f / (float)S);
    const float dstep = fmn * (1.0f / 127.0f);

    // zero histograms (their regions are untouched until consumed)
    sHU[lane] = 0; sHU[64 + lane] = 0;
    sHM[lane] = 0; sHM[64 + lane] = 0;
    if (lane == 0) { sHU[128] = 0; sHM[128] = 0; }

    // layer-1 fold: A_j = b1_j + o.W1_j ; B_j = d.W1_j (interleaved pairs)
    if (lane < 32) {
        const int j = lane;
        const float w0 = W1[j], w1 = W1[32 + j], w2 = W1[64 + j];
        ((float*)&sAB[j >> 1])[(j & 1)]     = b1[j] + ox * w0 + oy * w1 + oz * w2;
        ((float*)&sAB[j >> 1])[2 + (j & 1)] = dx * w0 + dy * w1 + dz * w2;
    }
    // acc-init bias per output col
    if (lane < 16) {
        float b = 0.0f;
        if (lane == 0) b = wsf[WS_B20];
        else if (lane <= 4) {
            const int c = lane - 1;
            b = wsf[WS_BF + c] + dx * Wd[c] + dy * Wd[4 + c] + dz * Wd[8 + c];
        }
        sBias[lane] = b;
    }
    __builtin_amdgcn_wave_barrier();

    // ---- per-lane fragments ----
    h16x2 Af[4], Bf[4];
#pragma unroll
    for (int m = 0; m < 4; ++m) {
        const float4 ab = sAB[kb * 4 + m];
        Af[m] = __builtin_amdgcn_cvt_pkrtz(ab.x, ab.y);
        Bf[m] = __builtin_amdgcn_cvt_pkrtz(ab.z, ab.w);
    }
    const float4 frw = ((const float4*)wsf)[lane];      // B-frag (16B/lane)
    const f16x8 bfrag = __builtin_bit_cast(f16x8, frw);
    const float bv = sBias[col16];
    f32x4 accB; accB[0] = bv; accB[1] = bv; accB[2] = bv; accB[3] = bv;

    // ---- MFMA MLP pass: 8 tiles of 16 samples, K=32, f16 in / f32 out ----
    auto mfma_pass = [&](auto tag) {
#pragma unroll
        for (int t = 0; t < 8; ++t) {
            float zs;
            if constexpr (decltype(tag)::fine) zs = sZf[t * 16 + col16];
            else                               zs = fmaf((float)(t * 16 + col16), dstep, nearv);
            const h16x2 z2 = __builtin_amdgcn_cvt_pkrtz(zs, zs);
            h16x2 h0 = pk_relu_f16(pk_fma_f16(Bf[0], z2, Af[0]));
            h16x2 h1 = pk_relu_f16(pk_fma_f16(Bf[1], z2, Af[1]));
            h16x2 h2 = pk_relu_f16(pk_fma_f16(Bf[2], z2, Af[2]));
            h16x2 h3 = pk_relu_f16(pk_fma_f16(Bf[3], z2, Af[3]));
            uint4 au;
            au.x = __builtin_bit_cast(unsigned int, h0);
            au.y = __builtin_bit_cast(unsigned int, h1);
            au.z = __builtin_bit_cast(unsigned int, h2);
            au.w = __builtin_bit_cast(unsigned int, h3);
            const f16x8 afrag = __builtin_bit_cast(f16x8, au);
            f32x4 acc = __builtin_amdgcn_mfma_f32_16x16x32_f16(afrag, bfrag, accB, 0, 0, 0);
            if (col16 < 5) {
#pragma unroll
                for (int i = 0; i < 4; ++i)
                    sStg[col16 * 132 + t * 16 + kb * 4 + i] = acc[i];
            }
        }
    };
    auto readback = [&](int p, float& sg, uint2& rgb) {
        const float c0 = sStg[0 * 132 + p];
        const float c1 = sStg[1 * 132 + p];
        const float c2 = sStg[2 * 132 + p];
        const float c3 = sStg[3 * 132 + p];
        const float c4 = sStg[4 * 132 + p];
        sg  = softplus_f(c0);
        rgb = pack_rgb(sigmoid_f(c1), sigmoid_f(c2), sigmoid_f(c3), sigmoid_f(c4));
    };

    // ---- coarse pass ----
    mfma_pass(CoarseTag{});
    __builtin_amdgcn_wave_barrier();
    float sgc0, sgc1; uint2 rc0, rc1;
    readback(2 * lane,     sgc0, rc0);
    readback(2 * lane + 1, sgc1, rc1);
    const float zc0 = fmaf((float)(2 * lane), dstep, nearv);
    const float zc1 = zc0 + dstep;
    __builtin_amdgcn_wave_barrier();    // stage consumed; cdf may overwrite

    // ---- coarse composite weights (for PDF) ----
    const float dc1 = (lane == 63) ? sample_dist : dstep;
    const float ec0 = __builtin_amdgcn_exp2f(dstep * sgc0 * -1.442695041f);
    const float ec1 = __builtin_amdgcn_exp2f(dc1 * sgc1 * -1.442695041f);
    const float alc0 = 1.f - ec0, alc1 = 1.f - ec1;
    const float vc0 = ec0 + 1e-15f, vc1 = ec1 + 1e-15f;
    const float incl = scan_mul_f(vc0 * vc1);
    float excl = __shfl_up(incl, 1, 64);
    if (lane == 0) excl = 1.f;
    const float wc0 = alc0 * excl;
    const float wc1 = alc1 * (excl * vc0);

    const float wnext = __shfl_down(wc0, 1, 64);      // w(2l+2)
    float p0 = wc1 + 1e-5f, p1 = wnext + 1e-5f;
    if (lane == 63) { p0 = 0.f; p1 = 0.f; }
    const float s01 = p0 + p1;
    const float cinc = scan_add_f(s01);
    const float total = __builtin_bit_cast(float,
        __builtin_amdgcn_readlane(__builtin_bit_cast(int, cinc), 63));
    const float rtot = __builtin_amdgcn_rcpf(total);
    const float cexcl = cinc - s01;
    if (lane < 63) {
        const float cdfA = (cexcl + p0) * rtot;
        const float cdfB = (cexcl + p0 + p1) * rtot;
        sCdf[2 * lane + 1] = cdfA;
        sCdf[2 * lane + 2] = cdfB;
        int cA = (int)ceilf(fmaf(128.f, cdfA, -0.5f));
        int cB = (int)ceilf(fmaf(128.f, cdfB, -0.5f));
        cA = min(max(cA, 0), 128); cB = min(max(cB, 0), 128);
        atomicAdd(&sHU[cA], 1);
        atomicAdd(&sHU[cB], 1);
    } else {
        sCdf[0] = 0.f;
        atomicAdd(&sHU[0], 1);
    }
    __builtin_amdgcn_wave_barrier();

    // ---- inds via histogram prefix; closed-form bin midpoints ----
    const int2 hu = *(const int2*)(sHU + 2 * lane);
    const int hs = hu.x + hu.y;
    const int hscan = scan_add_i(hs);
    const int hexcl = hscan - hs;
    const int indsA = hexcl + hu.x;
    const int indsB = hexcl + hs;

    auto lerp_z = [&](int inds, float u) -> float {
        const int below = inds - 1;
        const int above = min(inds, 126);
        const float cb = sCdf[below], ca = sCdf[above];
        const float bb = fmaf((float)below + 0.5f, dstep, nearv);
        const float ba = fmaf((float)above + 0.5f, dstep, nearv);
        float den = ca - cb;
        if (den < 1e-5f) den = 1.0f;
        const float t = (u - cb) * __builtin_amdgcn_rcpf(den);
        return bb + t * (ba - bb);
    };
    const float zf0 = lerp_z(indsA, ((float)(2 * lane) + 0.5f) * (1.0f / 128.f));
    const float zf1 = lerp_z(indsB, ((float)(2 * lane) + 1.5f) * (1.0f / 128.f));
    sZf[2 * lane]     = zf0;
    sZf[2 * lane + 1] = zf1;

    // rank of fine in coarse (closed form) + histogram
    const float inv_stepz = 127.0f / fmn;
    int r0 = (int)floorf((zf0 - nearv) * inv_stepz) + 1;
    int r1 = (int)floorf((zf1 - nearv) * inv_stepz) + 1;
    r0 = min(max(r0, 0), 128); r1 = min(max(r1, 0), 128);
    atomicAdd(&sHM[r0], 1);
    atomicAdd(&sHM[r1], 1);
    __builtin_amdgcn_wave_barrier();    // cdf consumed; fine stage may overwrite

    // ---- fine pass ----
    mfma_pass(FineTag{});
    __builtin_amdgcn_wave_barrier();
    float sgf0, sgf1; uint2 rf0, rf1;
    readback(2 * lane,     sgf0, rf0);
    readback(2 * lane + 1, sgf1, rf1);
    __builtin_amdgcn_wave_barrier();    // stage consumed before sorted writes

    // ---- merge ranks via histogram prefix; scatter sorted triples ----
    const int2 hm = *(const int2*)(sHM + 2 * lane);   // read precedes writes below
    const int ms = hm.x + hm.y;
    const int mscan = scan_add_i(ms);
    const int mexcl = mscan - ms;
    const int dC0 = 2 * lane + (mexcl + hm.x);
    const int dC1 = 2 * lane + 1 + (mexcl + ms);
    const int dF0 = 2 * lane + r0;
    const int dF1 = 2 * lane + 1 + r1;

    auto il = [](int d) { return ((d & 3) << 6) + (d >> 2); };
    {
        const int a0 = il(dC0), a1 = il(dC1), a2 = il(dF0), a3 = il(dF1);
        sZs[a0] = zc0; sSig[a0] = sgc0; sRgb[a0] = rc0;
        sZs[a1] = zc1; sSig[a1] = sgc1; sRgb[a1] = rc1;
        sZs[a2] = zf0; sSig[a2] = sgf0; sRgb[a2] = rf0;
        sZs[a3] = zf1; sSig[a3] = sgf1; sRgb[a3] = rf1;
    }
    __builtin_amdgcn_wave_barrier();

    // ---- final compositing: 4 sorted samples per lane (il4 reads) ----
    const float z0 = sZs[lane],        z1 = sZs[64 + lane];
    const float z2 = sZs[128 + lane],  z3 = sZs[192 + lane];
    const float g0 = sSig[lane],       g1 = sSig[64 + lane];
    const float g2 = sSig[128 + lane], g3 = sSig[192 + lane];
    const uint2 q0 = sRgb[lane],       q1 = sRgb[64 + lane];
    const uint2 q2 = sRgb[128 + lane], q3 = sRgb[192 + lane];

    const float znx = __shfl_down(z0, 1, 64);
    const float dd0 = z1 - z0;
    const float dd1 = z2 - z1;
    const float dd2 = z3 - z2;
    const float dd3 = (lane == 63) ? sample_dist : (znx - z3);

    const float e0 = __builtin_amdgcn_exp2f(dd0 * g0 * -1.442695041f);
    const float e1 = __builtin_amdgcn_exp2f(dd1 * g1 * -1.442695041f);
    const float e2 = __builtin_amdgcn_exp2f(dd2 * g2 * -1.442695041f);
    const float e3 = __builtin_amdgcn_exp2f(dd3 * g3 * -1.442695041f);
    const float al0 = 1.f - e0, al1 = 1.f - e1, al2 = 1.f - e2, al3 = 1.f - e3;
    const float v0 = e0 + 1e-15f, v1 = e1 + 1e-15f, v2 = e2 + 1e-15f, v3 = e3 + 1e-15f;

    const float incl2 = scan_mul_f(v0 * v1 * v2 * v3);
    float T0 = __shfl_up(incl2, 1, 64);
    if (lane == 0) T0 = 1.f;
    const float T1 = T0 * v0, T2 = T1 * v1, T3 = T2 * v2;
    const float w0 = al0 * T0, w1 = al1 * T1, w2 = al2 * T2, w3 = al3 * T3;

    const float inv_fn = 1.0f / fmn;
    const float oz0 = clampf((z0 - nearv) * inv_fn, 0.f, 1.f);
    const float oz1 = clampf((z1 - nearv) * inv_fn, 0.f, 1.f);
    const float oz2 = clampf((z2 - nearv) * inv_fn, 0.f, 1.f);
    const float oz3 = clampf((z3 - nearv) * inv_fn, 0.f, 1.f);

    float r0c[4], r1c[4], r2c[4], r3c[4];
    unpack_rgb(q0.x, q0.y, r0c);
    unpack_rgb(q1.x, q1.y, r1c);
    unpack_rgb(q2.x, q2.y, r2c);
    unpack_rgb(q3.x, q3.y, r3c);

    float vals[6];
#pragma unroll
    for (int c = 0; c < 4; ++c)
        vals[c] = w0 * r0c[c] + w1 * r1c[c] + w2 * r2c[c] + w3 * r3c[c];
    vals[4] = w0 * oz0 + w1 * oz1 + w2 * oz2 + w3 * oz3;
    vals[5] = w0 + w1 + w2 + w3;

#pragma unroll
    for (int q = 0; q < 6; ++q) vals[q] = scan_add_f(vals[q]);

    if (lane == 63) {
        const float wsum = vals[5];
#pragma unroll
        for (int c = 0; c < 4; ++c)
            out[ray * 4 + c] = vals[c] + (1.0f - wsum);
        out[4 * N_RAYS + ray] = vals[4];
        out[5 * N_RAYS + ray] = wsum;
    }
}

extern "C" void kernel_launch(void* const* d_in, const int* in_sizes, int n_in,
                              void* d_out, int out_size, void* d_ws, size_t ws_size,
                              hipStream_t stream) {
    const float* rays_o = (const float*)d_in[0];
    const float* rays_d = (const float*)d_in[1];
    const float* W1 = (const float*)d_in[2];
    const float* b1 = (const float*)d_in[3];
    const float* W2 = (const float*)d_in[4];
    const float* b2 = (const float*)d_in[5];
    const float* Wc = (const float*)d_in[6];
    const float* Wd = (const float*)d_in[7];
    const float* bc = (const float*)d_in[8];
    float* out = (float*)d_out;
    float* ws  = (float*)d_ws;

    hipLaunchKernelGGL(nerf_prep_kernel, dim3(1), dim3(64), 0, stream,
                       W2, b2, Wc, bc, ws);
    hipLaunchKernelGGL(nerf_render_kernel, dim3(N_RAYS / RPB), dim3(256), 0, stream,
                       rays_o, rays_d, W1, b1, Wd, ws, out);
}